// Round 7
// baseline (496.851 us; speedup 1.0000x reference)
//
#include <hip/hip_runtime.h>
#include <cstdint>
#include <cstddef>

typedef unsigned short u16;
typedef unsigned int u32;

#define NT 100000
#define NC 25000
#define ETT 800000
#define ECT 400000
#define SLOPE 0.2f
#define LOG2E 1.4426950408889634f
#define OFFS (NT + 4)           // padded stride for offset arrays (16B-aligned)

// direct global-atomic CSR build
#define NBLK 256                        // count/scatter blocks
#define CHT ((ETT + NBLK - 1) / NBLK)   // 3125 tt edges / block
#define CHC ((ECT + NBLK - 1) / NBLK)   // 1563 ct edges / block
#define NSB2 74                         // ceil(3*OFFS/4096) scan blocks
#define SCN (NSB2 * 4096)               // 303104 padded scan length (ints)
#define PER (SCN / NBLK)                // 1184 offs-finalize slice per scatter block

#define PT_BLK ((NT + 63) / 64)   // 1563 pre_t blocks (64 rows each)
#define CT_BLK ((NC + 63) / 64)   // 391 ctx blocks

typedef __attribute__((ext_vector_type(8))) short bf16x8;
typedef __attribute__((ext_vector_type(4))) float f32x4;

__device__ __forceinline__ u16 f2bf(float f) {
  u32 u = __float_as_uint(f);
  u32 r = (u >> 16) & 1u;
  return (u16)((u + 0x7fffu + r) >> 16);
}
__device__ __forceinline__ float lof(u32 p) { return __uint_as_float(p << 16); }
__device__ __forceinline__ float hif(u32 p) { return __uint_as_float(p & 0xffff0000u); }

// exclusive prefix of bsum[0..n) into s_bpre[0..256): consumers recompute the
// top-level scan in LDS (sub-us) instead of a dedicated kernel.
__device__ __forceinline__ void compute_bpre(const int* __restrict__ bsum,
                                             int* s_bpre, int n) {
  const int t = threadIdx.x;
  const int v = (t < n) ? bsum[t] : 0;
  s_bpre[t] = v;
  __syncthreads();
  for (int d = 1; d < 256; d <<= 1) {
    const int u = (t >= d) ? s_bpre[t - d] : 0;
    __syncthreads();
    s_bpre[t] += u;
    __syncthreads();
  }
  const int incl = s_bpre[t];
  __syncthreads();
  s_bpre[t] = incl - v;
  __syncthreads();
}

// ---------- K_A: deg-count (256) ∪ prep (4) ∪ pre_t (1563) ∪ ctx (391) ----------
// Count path: direct global atomics on deg[rel*OFFS+node] (L2-resident 1.2MB,
// ~8/node mean contention). Replaces the bucket histogram; overlaps transforms.
// Transform paths: register-blocked (4r x 8c / thread), activation staged
// TRANSPOSED -> VALU-bound (R6: 110 -> ~70us).
__global__ __launch_bounds__(256) void transform_count_kernel(
    const int* __restrict__ tt_src, const int* __restrict__ tt_dst,
    const int* __restrict__ ect_d, int* __restrict__ deg,
    const float* __restrict__ Wsd, const float* __restrict__ AsSd, const float* __restrict__ AdSd,
    const float* __restrict__ Wds, const float* __restrict__ AsDs, const float* __restrict__ AdDs,
    const float* __restrict__ Wout,
    u16* __restrict__ bf_sd, u16* __restrict__ bf_ds, u16* __restrict__ bf_out,
    const float* __restrict__ Wcd, const float* __restrict__ attD,
    const float* __restrict__ bsd, const float* __restrict__ bds, const float* __restrict__ bct,
    float* __restrict__ cbias,
    const float* __restrict__ x_t, const float* __restrict__ Wpt, const float* __restrict__ bpt,
    u16* __restrict__ h_t, float* __restrict__ aD,
    const float* __restrict__ x_c, const float* __restrict__ Wpc, const float* __restrict__ bpc,
    const float* __restrict__ Wcs, const float* __restrict__ attS,
    u16* __restrict__ hc_bf, float* __restrict__ aS_c)
{
  __shared__ __align__(16) char smem[51200];
  const int t = threadIdx.x;

  if (blockIdx.x < NBLK) {
    // ---------------- deg-count path ----------------
    const int b = blockIdx.x;
    const int lo = b * CHT, hi = min(lo + CHT, ETT);
    for (int i = lo + t; i < hi; i += 256) {
      atomicAdd(&deg[tt_dst[i]], 1);
      atomicAdd(&deg[OFFS + tt_src[i]], 1);
    }
    const int lo2 = b * CHC, hi2 = min(lo2 + CHC, ECT);
    for (int i = lo2 + t; i < hi2; i += 256)
      atomicAdd(&deg[2 * OFFS + ect_d[i]], 1);
    return;
  }

  const int b = blockIdx.x - NBLK;

  if (b < 4) {
    // ---------------- prep path ----------------
    if (b == 3) {
      if (t < 128) cbias[t] = 0.25f * bsd[t] + 0.25f * bds[t] + 0.5f * bct[t];
      return;
    }
    float* fS = (float*)smem;
    float* fD = fS + 512;
    const float* W = (b == 0) ? Wsd : (b == 1) ? Wds : Wout;
    const float* As = (b == 0) ? AsSd : AsDs;
    const float* Ad = (b == 0) ? AdSd : AdDs;
    u16* out = (b == 0) ? bf_sd : (b == 1) ? bf_ds : bf_out;
    const int tiles = (b == 2) ? 8 : 9;
    if (b < 2) {
      if (t < 128) {
        for (int hh = 0; hh < 4; ++hh) {
          float s1 = 0.f, s2 = 0.f;
          for (int c = 0; c < 32; ++c) {
            const float wv = W[t * 128 + hh * 32 + c];
            s1 = fmaf(wv, As[hh * 32 + c], s1);
            s2 = fmaf(wv, Ad[hh * 32 + c], s2);
          }
          fS[t * 4 + hh] = s1 * LOG2E; fD[t * 4 + hh] = s2 * LOG2E;
        }
      }
      __syncthreads();
    }
    const int total = tiles * 4 * 64 * 8;
    for (int i = t; i < total; i += 256) {
      const int j = i & 7, lane = (i >> 3) & 63, ks = (i >> 9) & 3, ti = i >> 11;
      const int k = ks * 32 + (lane >> 4) * 8 + j;
      const int n = ti * 16 + (lane & 15);
      float v;
      if (n < 128) v = W[k * 128 + n];
      else if (n < 132) v = fS[k * 4 + (n - 128)];
      else if (n < 136) v = fD[k * 4 + (n - 132)];
      else v = 0.f;
      out[i] = f2bf(v);
    }
    return;
  }

  if (b < 4 + PT_BLK) {
    // ---------------- pre_t path (64 rows/block, 4r x 8c / thread) ----------------
    float (*s_xt)[68] = (float(*)[68])smem;                 // 64 x 68 x4 = 17408
    float (*s_W)[128] = (float(*)[128])(smem + 17408);      // 32 x 128 x4 = 16384
    float* s_fold     = (float*)(smem + 17408 + 16384);     // 512 x4 = 2048
    const int row0 = (b - 4) * 64;
    for (int g = 0; g < 4; ++g) {
      const int lr = g * 16 + (t >> 4);
      const int k4 = (t & 15) * 4;
      const int grow = row0 + lr;
      float4 f = make_float4(0.f, 0.f, 0.f, 0.f);
      if (grow < NT) f = *(const float4*)(x_t + (size_t)grow * 64 + k4);
      s_xt[k4 + 0][lr] = f.x; s_xt[k4 + 1][lr] = f.y;
      s_xt[k4 + 2][lr] = f.z; s_xt[k4 + 3][lr] = f.w;
    }
    if (t < 128) {
      for (int hh = 0; hh < 4; ++hh) {
        float s = 0.f;
        for (int c = 0; c < 32; ++c)
          s = fmaf(Wcd[t * 128 + hh * 32 + c], attD[hh * 32 + c], s);
        s_fold[t * 4 + hh] = s * LOG2E;
      }
    }
    const int rg = t >> 4;        // row group: rows rg*4 .. rg*4+4
    const int cg = t & 15;        // col groups: cg*4 and cg*4+64
    float acc[4][8];
    for (int r = 0; r < 4; ++r)
      for (int j = 0; j < 8; ++j)
        acc[r][j] = bpt[cg * 4 + (j & 3) + (j >> 2) * 64];
    for (int kc = 0; kc < 64; kc += 32) {
      for (int j = 0; j < 4; ++j) {
        const int idx = t + j * 256;
        const int k = idx >> 5, c4 = (idx & 31) * 4;
        *(float4*)&s_W[k][c4] = *(const float4*)(Wpt + (size_t)(kc + k) * 128 + c4);
      }
      __syncthreads();
#pragma unroll 8
      for (int k = 0; k < 32; ++k) {
        const float4 xa = *(const float4*)&s_xt[kc + k][rg * 4];
        const float4 w0 = *(const float4*)&s_W[k][cg * 4];
        const float4 w1 = *(const float4*)&s_W[k][cg * 4 + 64];
        const float xr[4] = {xa.x, xa.y, xa.z, xa.w};
        for (int r = 0; r < 4; ++r) {
          acc[r][0] = fmaf(xr[r], w0.x, acc[r][0]);
          acc[r][1] = fmaf(xr[r], w0.y, acc[r][1]);
          acc[r][2] = fmaf(xr[r], w0.z, acc[r][2]);
          acc[r][3] = fmaf(xr[r], w0.w, acc[r][3]);
          acc[r][4] = fmaf(xr[r], w1.x, acc[r][4]);
          acc[r][5] = fmaf(xr[r], w1.y, acc[r][5]);
          acc[r][6] = fmaf(xr[r], w1.z, acc[r][6]);
          acc[r][7] = fmaf(xr[r], w1.w, acc[r][7]);
        }
      }
      __syncthreads();
    }
    for (int r = 0; r < 4; ++r) {
      const int grow = row0 + rg * 4 + r;
      float v[8];
      for (int j = 0; j < 8; ++j) v[j] = fmaxf(acc[r][j], 0.f);
      float p0 = 0.f, p1 = 0.f, p2 = 0.f, p3 = 0.f;
      for (int j = 0; j < 8; ++j) {
        const int col = cg * 4 + (j & 3) + ((j >> 2) * 64);
        const float4 f4 = *(const float4*)&s_fold[col * 4];
        p0 = fmaf(v[j], f4.x, p0); p1 = fmaf(v[j], f4.y, p1);
        p2 = fmaf(v[j], f4.z, p2); p3 = fmaf(v[j], f4.w, p3);
      }
      if (grow < NT) {
        uint2 pk;
        pk.x = (u32)f2bf(v[0]) | ((u32)f2bf(v[1]) << 16);
        pk.y = (u32)f2bf(v[2]) | ((u32)f2bf(v[3]) << 16);
        *(uint2*)(h_t + (size_t)grow * 128 + cg * 4) = pk;
        pk.x = (u32)f2bf(v[4]) | ((u32)f2bf(v[5]) << 16);
        pk.y = (u32)f2bf(v[6]) | ((u32)f2bf(v[7]) << 16);
        *(uint2*)(h_t + (size_t)grow * 128 + cg * 4 + 64) = pk;
      }
      for (int m = 1; m < 16; m <<= 1) {
        p0 += __shfl_xor(p0, m); p1 += __shfl_xor(p1, m);
        p2 += __shfl_xor(p2, m); p3 += __shfl_xor(p3, m);
      }
      if (cg == 0 && grow < NT)
        *(float4*)(aD + (size_t)grow * 4) = make_float4(p0, p1, p2, p3);
    }
    return;
  }

  // ---------------- ctx path (64 rows/block, 4r x 8c / thread) ----------------
  {
    float (*s_ht)[68]  = (float(*)[68])smem;                // 128 x 68 x4 = 34816
    float (*s_W2)[128] = (float(*)[128])(smem + 34816);     // 16384 (total 51200)
    float (*s_xc)[68]  = (float(*)[68])smem;                // alias: dead before s_ht writes
    const int row0 = (b - 4 - PT_BLK) * 64;
    for (int g = 0; g < 2; ++g) {
      const int lr = g * 32 + (t >> 3);
      const int k4 = (t & 7) * 4;
      const int grow = row0 + lr;
      float4 f = make_float4(0.f, 0.f, 0.f, 0.f);
      if (grow < NC) f = *(const float4*)(x_c + (size_t)grow * 32 + k4);
      s_xc[k4 + 0][lr] = f.x; s_xc[k4 + 1][lr] = f.y;
      s_xc[k4 + 2][lr] = f.z; s_xc[k4 + 3][lr] = f.w;
    }
    for (int j = 0; j < 4; ++j) {
      const int idx = t + j * 256;
      const int k = idx >> 5, c4 = (idx & 31) * 4;
      *(float4*)&s_W2[k][c4] = *(const float4*)(Wpc + (size_t)k * 128 + c4);
    }
    __syncthreads();
    const int rg = t >> 4, cg = t & 15;
    float acc1[4][8];
    for (int r = 0; r < 4; ++r)
      for (int j = 0; j < 8; ++j)
        acc1[r][j] = bpc[cg * 4 + (j & 3) + (j >> 2) * 64];
#pragma unroll 8
    for (int k = 0; k < 32; ++k) {
      const float4 xa = *(const float4*)&s_xc[k][rg * 4];
      const float4 w0 = *(const float4*)&s_W2[k][cg * 4];
      const float4 w1 = *(const float4*)&s_W2[k][cg * 4 + 64];
      const float xr[4] = {xa.x, xa.y, xa.z, xa.w};
      for (int r = 0; r < 4; ++r) {
        acc1[r][0] = fmaf(xr[r], w0.x, acc1[r][0]);
        acc1[r][1] = fmaf(xr[r], w0.y, acc1[r][1]);
        acc1[r][2] = fmaf(xr[r], w0.z, acc1[r][2]);
        acc1[r][3] = fmaf(xr[r], w0.w, acc1[r][3]);
        acc1[r][4] = fmaf(xr[r], w1.x, acc1[r][4]);
        acc1[r][5] = fmaf(xr[r], w1.y, acc1[r][5]);
        acc1[r][6] = fmaf(xr[r], w1.z, acc1[r][6]);
        acc1[r][7] = fmaf(xr[r], w1.w, acc1[r][7]);
      }
    }
    __syncthreads();                 // s_xc dead; safe to overwrite with s_ht
    for (int r = 0; r < 4; ++r) {
      const int lr = rg * 4 + r;
      for (int j = 0; j < 8; ++j) {
        const int col = cg * 4 + (j & 3) + ((j >> 2) * 64);
        s_ht[col][lr] = fmaxf(acc1[r][j], 0.f);
      }
    }
    for (int j = 0; j < 4; ++j) {
      const int idx = t + j * 256;
      const int k = idx >> 5, c4 = (idx & 31) * 4;
      *(float4*)&s_W2[k][c4] = *(const float4*)(Wcs + (size_t)k * 128 + c4);
    }
    __syncthreads();
    float acc2[4][8];
    for (int r = 0; r < 4; ++r)
      for (int j = 0; j < 8; ++j) acc2[r][j] = 0.f;
    for (int kc = 0; kc < 128; kc += 32) {
#pragma unroll 8
      for (int k = 0; k < 32; ++k) {
        const float4 xa = *(const float4*)&s_ht[kc + k][rg * 4];
        const float4 w0 = *(const float4*)&s_W2[k][cg * 4];
        const float4 w1 = *(const float4*)&s_W2[k][cg * 4 + 64];
        const float xr[4] = {xa.x, xa.y, xa.z, xa.w};
        for (int r = 0; r < 4; ++r) {
          acc2[r][0] = fmaf(xr[r], w0.x, acc2[r][0]);
          acc2[r][1] = fmaf(xr[r], w0.y, acc2[r][1]);
          acc2[r][2] = fmaf(xr[r], w0.z, acc2[r][2]);
          acc2[r][3] = fmaf(xr[r], w0.w, acc2[r][3]);
          acc2[r][4] = fmaf(xr[r], w1.x, acc2[r][4]);
          acc2[r][5] = fmaf(xr[r], w1.y, acc2[r][5]);
          acc2[r][6] = fmaf(xr[r], w1.z, acc2[r][6]);
          acc2[r][7] = fmaf(xr[r], w1.w, acc2[r][7]);
        }
      }
      if (kc < 96) {
        __syncthreads();
        for (int j = 0; j < 4; ++j) {
          const int idx = t + j * 256;
          const int k = idx >> 5, c4 = (idx & 31) * 4;
          *(float4*)&s_W2[k][c4] = *(const float4*)(Wcs + (size_t)(kc + 32 + k) * 128 + c4);
        }
        __syncthreads();
      }
    }
    const int h2 = cg >> 3;
    const float4 at0 = *(const float4*)(attS + cg * 4);
    const float4 at1 = *(const float4*)(attS + cg * 4 + 64);
    for (int r = 0; r < 4; ++r) {
      const int grow = row0 + rg * 4 + r;
      float pa = acc2[r][0] * at0.x + acc2[r][1] * at0.y +
                 acc2[r][2] * at0.z + acc2[r][3] * at0.w;
      float pb = acc2[r][4] * at1.x + acc2[r][5] * at1.y +
                 acc2[r][6] * at1.z + acc2[r][7] * at1.w;
      if (grow < NC) {
        uint2 pk;
        pk.x = (u32)f2bf(acc2[r][0]) | ((u32)f2bf(acc2[r][1]) << 16);
        pk.y = (u32)f2bf(acc2[r][2]) | ((u32)f2bf(acc2[r][3]) << 16);
        *(uint2*)(hc_bf + (size_t)grow * 128 + cg * 4) = pk;
        pk.x = (u32)f2bf(acc2[r][4]) | ((u32)f2bf(acc2[r][5]) << 16);
        pk.y = (u32)f2bf(acc2[r][6]) | ((u32)f2bf(acc2[r][7]) << 16);
        *(uint2*)(hc_bf + (size_t)grow * 128 + cg * 4 + 64) = pk;
      }
      for (int m = 1; m < 8; m <<= 1) {
        pa += __shfl_xor(pa, m);
        pb += __shfl_xor(pb, m);
      }
      if ((cg & 7) == 0 && grow < NC) {
        aS_c[(size_t)grow * 4 + h2] = pa * LOG2E;
        aS_c[(size_t)grow * 4 + 2 + h2] = pb * LOG2E;
      }
    }
  }
}

// ---------- scan_nodes: 4096-chunk exclusive scan over deg[SCN] ----------
// Writes partial scan to BOTH offs and cur (cur is the scatter cursor array);
// top-level prefix (bpre over 74 chunk sums) is added by consumers in LDS.
__global__ __launch_bounds__(256) void scan_nodes_kernel(const int* __restrict__ deg,
    int* __restrict__ offs, int* __restrict__ cur, int* __restrict__ bsum)
{
  const int t = threadIdx.x, b = blockIdx.x;
  const int idx = b * 4096 + t * 16;     // always < SCN (grid covers exactly)
  int v[16];
  int s = 0;
#pragma unroll
  for (int q = 0; q < 4; ++q) {
    const int4 qq = *(const int4*)(deg + idx + q * 4);
    v[q * 4 + 0] = s; s += qq.x;
    v[q * 4 + 1] = s; s += qq.y;
    v[q * 4 + 2] = s; s += qq.z;
    v[q * 4 + 3] = s; s += qq.w;
  }
  __shared__ int sh[256];
  sh[t] = s;
  __syncthreads();
  for (int d = 1; d < 256; d <<= 1) {
    const int u = (t >= d) ? sh[t - d] : 0;
    __syncthreads();
    sh[t] += u;
    __syncthreads();
  }
  const int excl = (t == 0) ? 0 : sh[t - 1];
#pragma unroll
  for (int q = 0; q < 4; ++q) {
    int4 qo;
    qo.x = excl + v[q * 4 + 0]; qo.y = excl + v[q * 4 + 1];
    qo.z = excl + v[q * 4 + 2]; qo.w = excl + v[q * 4 + 3];
    *(int4*)(offs + idx + q * 4) = qo;
    *(int4*)(cur + idx + q * 4) = qo;
  }
  if (t == 255) bsum[b] = sh[255];
}

// ---------- K_C: scatter (256 blocks) ∪ mfma_logits2 (1563 blocks) ----------
// scatter: el[pos] via global-atomic cursors (positions GLOBAL across the 3
// relations -- one unified big_el). Also finalizes offs += bpre per slice so
// downstream gather reads materialized offsets. Replaces bin + bucket_fill.
__global__ __launch_bounds__(256) void scatter_logits2_kernel(
    const int* __restrict__ tt_src, const int* __restrict__ tt_dst,
    const int* __restrict__ ect_s, const int* __restrict__ ect_d,
    int* __restrict__ offs, int* __restrict__ cur, const int* __restrict__ bsum,
    int* __restrict__ big_el,
    const short* __restrict__ A, const short* __restrict__ Bsd, const short* __restrict__ Bds,
    u16* __restrict__ hs, float* __restrict__ aSsd, float* __restrict__ aDsd,
    u16* __restrict__ hd, float* __restrict__ aSds, float* __restrict__ aDds, int M)
{
  __shared__ __align__(16) float ldsf[4][16][148];
  const int t = threadIdx.x;

  if (blockIdx.x < NBLK) {
    // ---------------- scatter path ----------------
    int* s_bpre = (int*)&ldsf[0][0][0];     // 256 ints
    compute_bpre(bsum, s_bpre, NSB2);
    const int b = blockIdx.x;
    // finalize offs slice (disjoint across blocks; gather reads it next dispatch)
    for (int i = t; i < PER; i += 256) {
      const int idx = b * PER + i;
      offs[idx] += s_bpre[idx >> 12];
    }
    const int lo = b * CHT, hi = min(lo + CHT, ETT);
    for (int i = lo + t; i < hi; i += 256) {
      const int s = tt_src[i], d = tt_dst[i];
      int p = atomicAdd(&cur[d], 1) + s_bpre[d >> 12];
      big_el[p] = s;
      p = atomicAdd(&cur[OFFS + s], 1) + s_bpre[(OFFS + s) >> 12];
      big_el[p] = d;
    }
    const int lo2 = b * CHC, hi2 = min(lo2 + CHC, ECT);
    for (int i = lo2 + t; i < hi2; i += 256) {
      const int dd = ect_d[i];
      const int p = atomicAdd(&cur[2 * OFFS + dd], 1) + s_bpre[(2 * OFFS + dd) >> 12];
      big_el[p] = ect_s[i];
    }
    return;
  }

  // ---------------- logits2 path ----------------
  float (*lds)[16][148] = ldsf;
  const int blk = blockIdx.x - NBLK;
  const int wv = t >> 6, lane = t & 63;
  const int quad = lane >> 4, l16 = lane & 15;
  const int row0 = blk * 64 + wv * 16;
  const int arow = min(row0 + l16, M - 1);
  const short* ap = A + (size_t)arow * 128 + quad * 8;
  bf16x8 af[4];
  for (int ks = 0; ks < 4; ++ks) af[ks] = *(const bf16x8*)(ap + ks * 32);
  const int row = row0 + l16;
  const int idx = lane & 7, rr = lane >> 3;
  for (int pass = 0; pass < 2; ++pass) {
    const short* B = pass ? Bds : Bsd;
    u16* outb = pass ? hd : hs;
    float* aS = pass ? aSds : aSsd;
    float* aD = pass ? aDds : aDsd;
    f32x4 acc[9];
    for (int ti = 0; ti < 9; ++ti) acc[ti] = (f32x4){0.f, 0.f, 0.f, 0.f};
    for (int ks = 0; ks < 4; ++ks)
      for (int ti = 0; ti < 9; ++ti) {
        const bf16x8 bf = *(const bf16x8*)(B + ((ti * 4 + ks) * 64 + lane) * 8);
        acc[ti] = __builtin_amdgcn_mfma_f32_16x16x32_bf16(af[ks], bf, acc[ti], 0, 0, 0);
      }
    for (int ti = 0; ti < 9; ++ti)
      for (int r = 0; r < 4; ++r)
        lds[wv][quad * 4 + r][ti * 16 + l16] = acc[ti][r];
    __syncthreads();
    if (row < M) {
      for (int g = 0; g < 8; ++g) {
        const f32x4 v = *(const f32x4*)&lds[wv][l16][g * 16 + quad * 4];
        uint2 pk;
        pk.x = (u32)f2bf(v[0]) | ((u32)f2bf(v[1]) << 16);
        pk.y = (u32)f2bf(v[2]) | ((u32)f2bf(v[3]) << 16);
        *(uint2*)(outb + (size_t)row * 128 + g * 16 + quad * 4) = pk;
      }
    }
    for (int p = 0; p < 2; ++p) {
      const int lr = p * 8 + rr;
      const int n = row0 + lr;
      if (n < M) {
        const float v = lds[wv][lr][128 + idx];
        if (idx < 4) aS[(size_t)n * 4 + idx] = v;
        else aD[(size_t)n * 4 + idx - 4] = v;
      }
    }
    __syncthreads();
  }
}

// ---------- MFMA GEMM, N=128 (8 tiles) + bias -> fp32 out ----------
__global__ __launch_bounds__(256) void mfma_out_kernel(
    const short* __restrict__ A, const short* __restrict__ B,
    const float* __restrict__ bias, float* __restrict__ out, int M)
{
  __shared__ __align__(16) float lds[4][16][132];
  const int wv = threadIdx.x >> 6, lane = threadIdx.x & 63;
  const int quad = lane >> 4, l16 = lane & 15;
  const int row0 = blockIdx.x * 64 + wv * 16;
  const int arow = min(row0 + l16, M - 1);
  const short* ap = A + (size_t)arow * 128 + quad * 8;
  bf16x8 af[4];
  for (int ks = 0; ks < 4; ++ks) af[ks] = *(const bf16x8*)(ap + ks * 32);
  f32x4 acc[8];
  for (int t = 0; t < 8; ++t) acc[t] = (f32x4){0.f, 0.f, 0.f, 0.f};
  for (int ks = 0; ks < 4; ++ks)
    for (int t = 0; t < 8; ++t) {
      const bf16x8 bf = *(const bf16x8*)(B + ((t * 4 + ks) * 64 + lane) * 8);
      acc[t] = __builtin_amdgcn_mfma_f32_16x16x32_bf16(af[ks], bf, acc[t], 0, 0, 0);
    }
  for (int t = 0; t < 8; ++t)
    for (int r = 0; r < 4; ++r)
      lds[wv][quad * 4 + r][t * 16 + l16] = acc[t][r];
  __syncthreads();
  const int row = row0 + l16;
  if (row < M) {
    for (int g = 0; g < 8; ++g) {
      const int col = g * 16 + quad * 4;
      f32x4 v = *(const f32x4*)&lds[wv][l16][col];
      const f32x4 b4 = *(const f32x4*)(bias + col);
      v = v + b4;
      *(f32x4*)(out + (size_t)row * 128 + col) = v;
    }
  }
}

// ---------- K5: fused 3-relation gather; 16-lane group per dst, 8 ch/lane ----------
// Round-0 depth-1 pipeline (fastest measured) with exp2f (logits LOG2E-prescaled).
// Gather is at its structural memory roofline (~3.5 TB/s on scattered 256B rows);
// deeper pipelining, occupancy, and request reduction all measured null (R0/R2/R3).
__device__ __forceinline__ void gat_pipe16(const int* __restrict__ off,
    const int* __restrict__ el, const float* __restrict__ aS, const float* __restrict__ aD,
    const u16* __restrict__ hb, int d, int h, int cb, int self_loop, float w,
    float* __restrict__ acc)
{
  const float ad = aD[(size_t)d * 4 + h];
  const int beg = off[d];
  const int m = off[d + 1] - beg;     // real edges
  const int cnt = m + self_loop;
  if (cnt <= 0) return;
  float den = 0.f;
  float a0 = 0.f, a1 = 0.f, a2 = 0.f, a3 = 0.f, a4 = 0.f, a5 = 0.f, a6 = 0.f, a7 = 0.f;
  int sB = (1 < m) ? el[beg + 1] : d;
  {
    const int sA0 = (0 < m) ? el[beg] : d;
    float eA = aS[(size_t)sA0 * 4 + h];
    uint4 pA = *(const uint4*)(hb + (size_t)sA0 * 128 + cb);
    for (int k = 0; k < cnt; ++k) {
      const int sC = (k + 2 < m) ? el[beg + k + 2] : d;
      const float eB = aS[(size_t)sB * 4 + h];
      const uint4 pB = *(const uint4*)(hb + (size_t)sB * 128 + cb);
      float ea = eA + ad;
      ea = ea > 0.f ? ea : SLOPE * ea;
      const float ex = exp2f(ea);
      den += ex;
      a0 = fmaf(ex, lof(pA.x), a0); a1 = fmaf(ex, hif(pA.x), a1);
      a2 = fmaf(ex, lof(pA.y), a2); a3 = fmaf(ex, hif(pA.y), a3);
      a4 = fmaf(ex, lof(pA.z), a4); a5 = fmaf(ex, hif(pA.z), a5);
      a6 = fmaf(ex, lof(pA.w), a6); a7 = fmaf(ex, hif(pA.w), a7);
      eA = eB; pA = pB; sB = sC;
    }
  }
  const float s = w / den;            // den > 0 since cnt > 0
  acc[0] = fmaf(a0, s, acc[0]); acc[1] = fmaf(a1, s, acc[1]);
  acc[2] = fmaf(a2, s, acc[2]); acc[3] = fmaf(a3, s, acc[3]);
  acc[4] = fmaf(a4, s, acc[4]); acc[5] = fmaf(a5, s, acc[5]);
  acc[6] = fmaf(a6, s, acc[6]); acc[7] = fmaf(a7, s, acc[7]);
}

__global__ __launch_bounds__(256) void gather_all_kernel(
    const int* __restrict__ off_f, const int* __restrict__ el_f,
    const float* __restrict__ aS_sd, const float* __restrict__ aD_sd, const u16* __restrict__ hs,
    const int* __restrict__ off_r, const int* __restrict__ el_r,
    const float* __restrict__ aS_ds, const float* __restrict__ aD_ds, const u16* __restrict__ hd,
    const int* __restrict__ off_c, const int* __restrict__ el_c,
    const float* __restrict__ aS_ct, const float* __restrict__ aD_ct, const u16* __restrict__ hc,
    const u16* __restrict__ skip, const float* __restrict__ cbias, u16* __restrict__ x)
{
  const int d = blockIdx.x * 16 + (threadIdx.x >> 4);
  if (d >= NT) return;
  const int lg = threadIdx.x & 15;    // lane in group
  const int h = lg >> 2;              // head for this lane's channels
  const int cb = lg * 8;              // channel base (8 channels per lane)
  float acc[8];
  for (int i = 0; i < 8; ++i) acc[i] = 0.f;
  gat_pipe16(off_f, el_f, aS_sd, aD_sd, hs, d, h, cb, 1, 0.25f, acc);
  gat_pipe16(off_r, el_r, aS_ds, aD_ds, hd, d, h, cb, 1, 0.25f, acc);
  gat_pipe16(off_c, el_c, aS_ct, aD_ct, hc, d, h, cb, 0, 0.5f, acc);
  const uint4 sk = *(const uint4*)(skip + (size_t)d * 128 + cb);
  const float4 cb0 = *(const float4*)(cbias + cb);
  const float4 cb1 = *(const float4*)(cbias + cb + 4);
  const float o0 = fmaxf(acc[0] + cb0.x + lof(sk.x), 0.f);
  const float o1 = fmaxf(acc[1] + cb0.y + hif(sk.x), 0.f);
  const float o2 = fmaxf(acc[2] + cb0.z + lof(sk.y), 0.f);
  const float o3 = fmaxf(acc[3] + cb0.w + hif(sk.y), 0.f);
  const float o4 = fmaxf(acc[4] + cb1.x + lof(sk.z), 0.f);
  const float o5 = fmaxf(acc[5] + cb1.y + hif(sk.z), 0.f);
  const float o6 = fmaxf(acc[6] + cb1.z + lof(sk.w), 0.f);
  const float o7 = fmaxf(acc[7] + cb1.w + hif(sk.w), 0.f);
  uint4 r;
  r.x = (u32)f2bf(o0) | ((u32)f2bf(o1) << 16);
  r.y = (u32)f2bf(o2) | ((u32)f2bf(o3) << 16);
  r.z = (u32)f2bf(o4) | ((u32)f2bf(o5) << 16);
  r.w = (u32)f2bf(o6) | ((u32)f2bf(o7) << 16);
  *(uint4*)(x + (size_t)d * 128 + cb) = r;
}

extern "C" void kernel_launch(void* const* d_in, const int* in_sizes, int n_in,
                              void* d_out, int out_size, void* d_ws, size_t ws_size,
                              hipStream_t stream)
{
  const float* x_t   = (const float*)d_in[0];
  const float* x_c   = (const float*)d_in[1];
  const int*   e_tt  = (const int*)d_in[2];
  const int*   ect_s = (const int*)d_in[3];
  const int*   ect_d = (const int*)d_in[4];
  const float* Wpt = (const float*)d_in[5];   const float* bpt = (const float*)d_in[6];
  const float* Wpc = (const float*)d_in[7];   const float* bpc = (const float*)d_in[8];
  const float* Wsd = (const float*)d_in[9];   const float* As_sd = (const float*)d_in[10];
  const float* Ad_sd = (const float*)d_in[11]; const float* bsd = (const float*)d_in[12];
  const float* Wds = (const float*)d_in[13];  const float* As_ds = (const float*)d_in[14];
  const float* Ad_ds = (const float*)d_in[15]; const float* bds = (const float*)d_in[16];
  const float* Wcs = (const float*)d_in[17];  const float* Wcd = (const float*)d_in[18];
  const float* As_ct = (const float*)d_in[19]; const float* Ad_ct = (const float*)d_in[20];
  const float* bct = (const float*)d_in[21];
  const float* Wout = (const float*)d_in[22]; const float* bout = (const float*)d_in[23];

  // workspace
  char* p = (char*)d_ws;
  size_t off = 0;
  auto alloc = [&](size_t bytes) { char* r = p + off; off += (bytes + 255) & ~(size_t)255; return r; };
  u16* ht_bf   = (u16*)alloc((size_t)NT * 128 * 2);
  u16* hs_bf   = (u16*)alloc((size_t)NT * 128 * 2);
  u16* hd_bf   = (u16*)alloc((size_t)NT * 128 * 2);
  u16* hc_bf   = (u16*)alloc((size_t)NC * 128 * 2);
  u16* x_bf    = (u16*)alloc((size_t)NT * 128 * 2);
  float* aS_sd = (float*)alloc((size_t)NT * 4 * 4);
  float* aD_sd = (float*)alloc((size_t)NT * 4 * 4);
  float* aS_ds = (float*)alloc((size_t)NT * 4 * 4);
  float* aD_ds = (float*)alloc((size_t)NT * 4 * 4);
  float* aS_ct = (float*)alloc((size_t)NC * 4 * 4);
  float* aD_ct = (float*)alloc((size_t)NT * 4 * 4);
  int* deg     = (int*)alloc((size_t)SCN * 4);
  int* offs    = (int*)alloc((size_t)SCN * 4);
  int* cur     = (int*)alloc((size_t)SCN * 4);
  int* big_el  = (int*)alloc((size_t)(2 * ETT + ECT) * 4);
  int* bsum    = (int*)alloc((size_t)NSB2 * 4);
  float* cbias   = (float*)alloc(128 * 4);
  u16* bfrag_sd  = (u16*)alloc((size_t)9 * 4 * 64 * 8 * 2);
  u16* bfrag_ds  = (u16*)alloc((size_t)9 * 4 * 64 * 8 * 2);
  u16* bfrag_out = (u16*)alloc((size_t)8 * 4 * 64 * 8 * 2);

  const int* tt_src = e_tt;
  const int* tt_dst = e_tt + ETT;

  const int gM = (NT + 63) / 64;       // 1563 (MFMA blocks)

  // zero deg (padded to SCN so the scan needs no bounds checks)
  hipMemsetAsync(deg, 0, (size_t)SCN * 4, stream);

  // K_A: deg-count ∪ prep ∪ pre_t ∪ ctx (independent paths, one dispatch)
  transform_count_kernel<<<NBLK + 4 + PT_BLK + CT_BLK, 256, 0, stream>>>(
      tt_src, tt_dst, ect_d, deg,
      Wsd, As_sd, Ad_sd, Wds, As_ds, Ad_ds, Wout,
      bfrag_sd, bfrag_ds, bfrag_out,
      Wcd, Ad_ct, bsd, bds, bct, cbias,
      x_t, Wpt, bpt, ht_bf, aD_ct,
      x_c, Wpc, bpc, Wcs, As_ct, hc_bf, aS_ct);

  // node-level scan (74 blocks; bpre recomputed by consumers in LDS)
  scan_nodes_kernel<<<NSB2, 256, 0, stream>>>(deg, offs, cur, bsum);

  // K_C: scatter ∪ sd/ds MFMA GEMMs+logits (independent, one dispatch)
  scatter_logits2_kernel<<<NBLK + gM, 256, 0, stream>>>(
      tt_src, tt_dst, ect_s, ect_d, offs, cur, bsum, big_el,
      (const short*)ht_bf, (const short*)bfrag_sd, (const short*)bfrag_ds,
      hs_bf, aS_sd, aD_sd, hd_bf, aS_ds, aD_ds, NT);

  // fused gather (sd + ds + ct + cbias + skip + relu) -> x_bf
  // offs entries are GLOBAL positions into the unified big_el.
  gather_all_kernel<<<(NT + 15) / 16, 256, 0, stream>>>(
      offs, big_el, aS_sd, aD_sd, hs_bf,
      offs + OFFS, big_el, aS_ds, aD_ds, hd_bf,
      offs + 2 * OFFS, big_el, aS_ct, aD_ct, hc_bf,
      ht_bf, cbias, x_bf);

  // final MFMA GEMM -> d_out (fp32)
  mfma_out_kernel<<<gM, 256, 0, stream>>>((const short*)x_bf, (const short*)bfrag_out,
                                          bout, (float*)d_out, NT);
}

// Round 9
// 409.720 us; speedup vs baseline: 1.2127x; 1.2127x over previous
//
#include <hip/hip_runtime.h>
#include <cstdint>
#include <cstddef>

typedef unsigned short u16;
typedef unsigned int u32;

#define NT 100000
#define NC 25000
#define ETT 800000
#define ECT 400000
#define SLOPE 0.2f
#define LOG2E 1.4426950408889634f
#define OFFS (NT + 4)           // padded stride for offset arrays (16B-aligned)

// bucket-binned CSR build (R6 design: block-exclusive bin sub-segments keep
// dirty lines XCD-local; R7's global scatter had 20x HBM write amplification)
#define NBK 782                 // ceil(NT/128) buckets of 128 nodes
#define NBLK 256                // binning blocks
#define CHT ((ETT + NBLK - 1) / NBLK)   // 3125 tt edges / block
#define CHC ((ECT + NBLK - 1) / NBLK)   // 1563 ct edges / block
#define TOTC (3 * NBK * NBLK)           // 600576 counts
#define NSB ((TOTC + 4095) / 4096)      // 147 scan blocks
#define FILL_CAP 4096                   // LDS staging capacity for bucket_fill (ints)

#define PT_BLK ((NT + 63) / 64)   // 1563 pre_t blocks (64 rows each)
#define CT_BLK ((NC + 63) / 64)   // 391 ctx blocks

// logits2 split across the two CSR dispatches; gather/out 2-stage pipeline
#define LROWS1 782                      // logits2 blocks in K_C1 (rows < 50048)
#define LROWS2 781                      // logits2 blocks in K_C2 (rows >= 50048)
#define GOH 50048                       // gather/out split point (782*64, /16 exact)
#define G1BLK (GOH / 16)                // 3128 gather blocks, dst < GOH
#define G2BLK ((NT - GOH + 15) / 16)    // 3123 gather blocks, dst >= GOH
#define OB1 (GOH / 64)                  // 782 out blocks, rows < GOH
#define OB2 ((NT - GOH + 63) / 64)      // 781 out blocks, rows >= GOH

typedef __attribute__((ext_vector_type(8))) short bf16x8;
typedef __attribute__((ext_vector_type(4))) float f32x4;

__device__ __forceinline__ u16 f2bf(float f) {
  u32 u = __float_as_uint(f);
  u32 r = (u >> 16) & 1u;
  return (u16)((u + 0x7fffu + r) >> 16);
}
__device__ __forceinline__ float lof(u32 p) { return __uint_as_float(p << 16); }
__device__ __forceinline__ float hif(u32 p) { return __uint_as_float(p & 0xffff0000u); }

// exclusive prefix of bsum[0..NSB) into s_bpre[0..256)
__device__ __forceinline__ void compute_bpre(const int* __restrict__ bsum, int* s_bpre) {
  const int t = threadIdx.x;
  const int v = (t < NSB) ? bsum[t] : 0;
  s_bpre[t] = v;
  __syncthreads();
  for (int d = 1; d < 256; d <<= 1) {
    const int u = (t >= d) ? s_bpre[t - d] : 0;
    __syncthreads();
    s_bpre[t] += u;
    __syncthreads();
  }
  const int incl = s_bpre[t];
  __syncthreads();
  s_bpre[t] = incl - v;
  __syncthreads();
}

// ---------- K_A: hist (256) ∪ prep (4) ∪ pre_t (1563) ∪ ctx (391) ----------
__global__ __launch_bounds__(256) void transform_hist_kernel(
    const int* __restrict__ tt_src, const int* __restrict__ tt_dst,
    const int* __restrict__ ect_d, int* __restrict__ cntblk,
    const float* __restrict__ Wsd, const float* __restrict__ AsSd, const float* __restrict__ AdSd,
    const float* __restrict__ Wds, const float* __restrict__ AsDs, const float* __restrict__ AdDs,
    const float* __restrict__ Wout,
    u16* __restrict__ bf_sd, u16* __restrict__ bf_ds, u16* __restrict__ bf_out,
    const float* __restrict__ Wcd, const float* __restrict__ attD,
    const float* __restrict__ bsd, const float* __restrict__ bds, const float* __restrict__ bct,
    float* __restrict__ cbias,
    const float* __restrict__ x_t, const float* __restrict__ Wpt, const float* __restrict__ bpt,
    u16* __restrict__ h_t, float* __restrict__ aD,
    const float* __restrict__ x_c, const float* __restrict__ Wpc, const float* __restrict__ bpc,
    const float* __restrict__ Wcs, const float* __restrict__ attS,
    u16* __restrict__ hc_bf, float* __restrict__ aS_c)
{
  __shared__ __align__(16) char smem[51200];
  const int t = threadIdx.x;

  if (blockIdx.x < NBLK) {
    // ---------------- hist path ----------------
    int* h = (int*)smem;               // 2346 ints
    const int b = blockIdx.x;
    for (int i = t; i < 3 * NBK; i += 256) h[i] = 0;
    __syncthreads();
    const int lo = b * CHT, hi = min(lo + CHT, ETT);
    for (int i = lo + t; i < hi; i += 256) {
      atomicAdd(&h[tt_dst[i] >> 7], 1);
      atomicAdd(&h[NBK + (tt_src[i] >> 7)], 1);
    }
    const int lo2 = b * CHC, hi2 = min(lo2 + CHC, ECT);
    for (int i = lo2 + t; i < hi2; i += 256)
      atomicAdd(&h[2 * NBK + (ect_d[i] >> 7)], 1);
    __syncthreads();
    for (int i = t; i < 3 * NBK; i += 256)
      cntblk[(size_t)i * NBLK + b] = h[i];
    return;
  }

  const int b = blockIdx.x - NBLK;

  if (b < 4) {
    // ---------------- prep path ----------------
    if (b == 3) {
      if (t < 128) cbias[t] = 0.25f * bsd[t] + 0.25f * bds[t] + 0.5f * bct[t];
      return;
    }
    float* fS = (float*)smem;
    float* fD = fS + 512;
    const float* W = (b == 0) ? Wsd : (b == 1) ? Wds : Wout;
    const float* As = (b == 0) ? AsSd : AsDs;
    const float* Ad = (b == 0) ? AdSd : AdDs;
    u16* out = (b == 0) ? bf_sd : (b == 1) ? bf_ds : bf_out;
    const int tiles = (b == 2) ? 8 : 9;
    if (b < 2) {
      if (t < 128) {
        for (int hh = 0; hh < 4; ++hh) {
          float s1 = 0.f, s2 = 0.f;
          for (int c = 0; c < 32; ++c) {
            const float wv = W[t * 128 + hh * 32 + c];
            s1 = fmaf(wv, As[hh * 32 + c], s1);
            s2 = fmaf(wv, Ad[hh * 32 + c], s2);
          }
          fS[t * 4 + hh] = s1 * LOG2E; fD[t * 4 + hh] = s2 * LOG2E;
        }
      }
      __syncthreads();
    }
    const int total = tiles * 4 * 64 * 8;
    for (int i = t; i < total; i += 256) {
      const int j = i & 7, lane = (i >> 3) & 63, ks = (i >> 9) & 3, ti = i >> 11;
      const int k = ks * 32 + (lane >> 4) * 8 + j;
      const int n = ti * 16 + (lane & 15);
      float v;
      if (n < 128) v = W[k * 128 + n];
      else if (n < 132) v = fS[k * 4 + (n - 128)];
      else if (n < 136) v = fD[k * 4 + (n - 132)];
      else v = 0.f;
      out[i] = f2bf(v);
    }
    return;
  }

  if (b < 4 + PT_BLK) {
    // ---------------- pre_t path (64 rows/block, 4r x 8c / thread) ----------------
    float (*s_xt)[68] = (float(*)[68])smem;                 // 64 x 68 x4 = 17408
    float (*s_W)[128] = (float(*)[128])(smem + 17408);      // 32 x 128 x4 = 16384
    float* s_fold     = (float*)(smem + 17408 + 16384);     // 512 x4 = 2048
    const int row0 = (b - 4) * 64;
    for (int g = 0; g < 4; ++g) {
      const int lr = g * 16 + (t >> 4);
      const int k4 = (t & 15) * 4;
      const int grow = row0 + lr;
      float4 f = make_float4(0.f, 0.f, 0.f, 0.f);
      if (grow < NT) f = *(const float4*)(x_t + (size_t)grow * 64 + k4);
      s_xt[k4 + 0][lr] = f.x; s_xt[k4 + 1][lr] = f.y;
      s_xt[k4 + 2][lr] = f.z; s_xt[k4 + 3][lr] = f.w;
    }
    if (t < 128) {
      for (int hh = 0; hh < 4; ++hh) {
        float s = 0.f;
        for (int c = 0; c < 32; ++c)
          s = fmaf(Wcd[t * 128 + hh * 32 + c], attD[hh * 32 + c], s);
        s_fold[t * 4 + hh] = s * LOG2E;
      }
    }
    const int rg = t >> 4;        // row group
    const int cg = t & 15;        // col groups cg*4 and cg*4+64
    float acc[4][8];
    for (int r = 0; r < 4; ++r)
      for (int j = 0; j < 8; ++j)
        acc[r][j] = bpt[cg * 4 + (j & 3) + (j >> 2) * 64];
    for (int kc = 0; kc < 64; kc += 32) {
      for (int j = 0; j < 4; ++j) {
        const int idx = t + j * 256;
        const int k = idx >> 5, c4 = (idx & 31) * 4;
        *(float4*)&s_W[k][c4] = *(const float4*)(Wpt + (size_t)(kc + k) * 128 + c4);
      }
      __syncthreads();
#pragma unroll 8
      for (int k = 0; k < 32; ++k) {
        const float4 xa = *(const float4*)&s_xt[kc + k][rg * 4];
        const float4 w0 = *(const float4*)&s_W[k][cg * 4];
        const float4 w1 = *(const float4*)&s_W[k][cg * 4 + 64];
        const float xr[4] = {xa.x, xa.y, xa.z, xa.w};
        for (int r = 0; r < 4; ++r) {
          acc[r][0] = fmaf(xr[r], w0.x, acc[r][0]);
          acc[r][1] = fmaf(xr[r], w0.y, acc[r][1]);
          acc[r][2] = fmaf(xr[r], w0.z, acc[r][2]);
          acc[r][3] = fmaf(xr[r], w0.w, acc[r][3]);
          acc[r][4] = fmaf(xr[r], w1.x, acc[r][4]);
          acc[r][5] = fmaf(xr[r], w1.y, acc[r][5]);
          acc[r][6] = fmaf(xr[r], w1.z, acc[r][6]);
          acc[r][7] = fmaf(xr[r], w1.w, acc[r][7]);
        }
      }
      __syncthreads();
    }
    for (int r = 0; r < 4; ++r) {
      const int grow = row0 + rg * 4 + r;
      float v[8];
      for (int j = 0; j < 8; ++j) v[j] = fmaxf(acc[r][j], 0.f);
      float p0 = 0.f, p1 = 0.f, p2 = 0.f, p3 = 0.f;
      for (int j = 0; j < 8; ++j) {
        const int col = cg * 4 + (j & 3) + ((j >> 2) * 64);
        const float4 f4 = *(const float4*)&s_fold[col * 4];
        p0 = fmaf(v[j], f4.x, p0); p1 = fmaf(v[j], f4.y, p1);
        p2 = fmaf(v[j], f4.z, p2); p3 = fmaf(v[j], f4.w, p3);
      }
      if (grow < NT) {
        uint2 pk;
        pk.x = (u32)f2bf(v[0]) | ((u32)f2bf(v[1]) << 16);
        pk.y = (u32)f2bf(v[2]) | ((u32)f2bf(v[3]) << 16);
        *(uint2*)(h_t + (size_t)grow * 128 + cg * 4) = pk;
        pk.x = (u32)f2bf(v[4]) | ((u32)f2bf(v[5]) << 16);
        pk.y = (u32)f2bf(v[6]) | ((u32)f2bf(v[7]) << 16);
        *(uint2*)(h_t + (size_t)grow * 128 + cg * 4 + 64) = pk;
      }
      for (int m = 1; m < 16; m <<= 1) {
        p0 += __shfl_xor(p0, m); p1 += __shfl_xor(p1, m);
        p2 += __shfl_xor(p2, m); p3 += __shfl_xor(p3, m);
      }
      if (cg == 0 && grow < NT)
        *(float4*)(aD + (size_t)grow * 4) = make_float4(p0, p1, p2, p3);
    }
    return;
  }

  // ---------------- ctx path (64 rows/block, 4r x 8c / thread) ----------------
  {
    float (*s_ht)[68]  = (float(*)[68])smem;                // 128 x 68 x4 = 34816
    float (*s_W2)[128] = (float(*)[128])(smem + 34816);     // 16384 (total 51200)
    float (*s_xc)[68]  = (float(*)[68])smem;                // alias: dead before s_ht writes
    const int row0 = (b - 4 - PT_BLK) * 64;
    for (int g = 0; g < 2; ++g) {
      const int lr = g * 32 + (t >> 3);
      const int k4 = (t & 7) * 4;
      const int grow = row0 + lr;
      float4 f = make_float4(0.f, 0.f, 0.f, 0.f);
      if (grow < NC) f = *(const float4*)(x_c + (size_t)grow * 32 + k4);
      s_xc[k4 + 0][lr] = f.x; s_xc[k4 + 1][lr] = f.y;
      s_xc[k4 + 2][lr] = f.z; s_xc[k4 + 3][lr] = f.w;
    }
    for (int j = 0; j < 4; ++j) {
      const int idx = t + j * 256;
      const int k = idx >> 5, c4 = (idx & 31) * 4;
      *(float4*)&s_W2[k][c4] = *(const float4*)(Wpc + (size_t)k * 128 + c4);
    }
    __syncthreads();
    const int rg = t >> 4, cg = t & 15;
    float acc1[4][8];
    for (int r = 0; r < 4; ++r)
      for (int j = 0; j < 8; ++j)
        acc1[r][j] = bpc[cg * 4 + (j & 3) + (j >> 2) * 64];
#pragma unroll 8
    for (int k = 0; k < 32; ++k) {
      const float4 xa = *(const float4*)&s_xc[k][rg * 4];
      const float4 w0 = *(const float4*)&s_W2[k][cg * 4];
      const float4 w1 = *(const float4*)&s_W2[k][cg * 4 + 64];
      const float xr[4] = {xa.x, xa.y, xa.z, xa.w};
      for (int r = 0; r < 4; ++r) {
        acc1[r][0] = fmaf(xr[r], w0.x, acc1[r][0]);
        acc1[r][1] = fmaf(xr[r], w0.y, acc1[r][1]);
        acc1[r][2] = fmaf(xr[r], w0.z, acc1[r][2]);
        acc1[r][3] = fmaf(xr[r], w0.w, acc1[r][3]);
        acc1[r][4] = fmaf(xr[r], w1.x, acc1[r][4]);
        acc1[r][5] = fmaf(xr[r], w1.y, acc1[r][5]);
        acc1[r][6] = fmaf(xr[r], w1.z, acc1[r][6]);
        acc1[r][7] = fmaf(xr[r], w1.w, acc1[r][7]);
      }
    }
    __syncthreads();                 // s_xc dead
    for (int r = 0; r < 4; ++r) {
      const int lr = rg * 4 + r;
      for (int j = 0; j < 8; ++j) {
        const int col = cg * 4 + (j & 3) + ((j >> 2) * 64);
        s_ht[col][lr] = fmaxf(acc1[r][j], 0.f);
      }
    }
    for (int j = 0; j < 4; ++j) {
      const int idx = t + j * 256;
      const int k = idx >> 5, c4 = (idx & 31) * 4;
      *(float4*)&s_W2[k][c4] = *(const float4*)(Wcs + (size_t)k * 128 + c4);
    }
    __syncthreads();
    float acc2[4][8];
    for (int r = 0; r < 4; ++r)
      for (int j = 0; j < 8; ++j) acc2[r][j] = 0.f;
    for (int kc = 0; kc < 128; kc += 32) {
#pragma unroll 8
      for (int k = 0; k < 32; ++k) {
        const float4 xa = *(const float4*)&s_ht[kc + k][rg * 4];
        const float4 w0 = *(const float4*)&s_W2[k][cg * 4];
        const float4 w1 = *(const float4*)&s_W2[k][cg * 4 + 64];
        const float xr[4] = {xa.x, xa.y, xa.z, xa.w};
        for (int r = 0; r < 4; ++r) {
          acc2[r][0] = fmaf(xr[r], w0.x, acc2[r][0]);
          acc2[r][1] = fmaf(xr[r], w0.y, acc2[r][1]);
          acc2[r][2] = fmaf(xr[r], w0.z, acc2[r][2]);
          acc2[r][3] = fmaf(xr[r], w0.w, acc2[r][3]);
          acc2[r][4] = fmaf(xr[r], w1.x, acc2[r][4]);
          acc2[r][5] = fmaf(xr[r], w1.y, acc2[r][5]);
          acc2[r][6] = fmaf(xr[r], w1.z, acc2[r][6]);
          acc2[r][7] = fmaf(xr[r], w1.w, acc2[r][7]);
        }
      }
      if (kc < 96) {
        __syncthreads();
        for (int j = 0; j < 4; ++j) {
          const int idx = t + j * 256;
          const int k = idx >> 5, c4 = (idx & 31) * 4;
          *(float4*)&s_W2[k][c4] = *(const float4*)(Wcs + (size_t)(kc + 32 + k) * 128 + c4);
        }
        __syncthreads();
      }
    }
    const int h2 = cg >> 3;
    const float4 at0 = *(const float4*)(attS + cg * 4);
    const float4 at1 = *(const float4*)(attS + cg * 4 + 64);
    for (int r = 0; r < 4; ++r) {
      const int grow = row0 + rg * 4 + r;
      float pa = acc2[r][0] * at0.x + acc2[r][1] * at0.y +
                 acc2[r][2] * at0.z + acc2[r][3] * at0.w;
      float pb = acc2[r][4] * at1.x + acc2[r][5] * at1.y +
                 acc2[r][6] * at1.z + acc2[r][7] * at1.w;
      if (grow < NC) {
        uint2 pk;
        pk.x = (u32)f2bf(acc2[r][0]) | ((u32)f2bf(acc2[r][1]) << 16);
        pk.y = (u32)f2bf(acc2[r][2]) | ((u32)f2bf(acc2[r][3]) << 16);
        *(uint2*)(hc_bf + (size_t)grow * 128 + cg * 4) = pk;
        pk.x = (u32)f2bf(acc2[r][4]) | ((u32)f2bf(acc2[r][5]) << 16);
        pk.y = (u32)f2bf(acc2[r][6]) | ((u32)f2bf(acc2[r][7]) << 16);
        *(uint2*)(hc_bf + (size_t)grow * 128 + cg * 4 + 64) = pk;
      }
      for (int m = 1; m < 8; m <<= 1) {
        pa += __shfl_xor(pa, m);
        pb += __shfl_xor(pb, m);
      }
      if ((cg & 7) == 0 && grow < NC) {
        aS_c[(size_t)grow * 4 + h2] = pa * LOG2E;
        aS_c[(size_t)grow * 4 + 2 + h2] = pb * LOG2E;
      }
    }
  }
}

// ---------- scan2_blk: 4096-chunk exclusive scan (partial) + chunk totals ----------
__global__ __launch_bounds__(256) void scan2_blk_kernel(const int* __restrict__ in,
    int* __restrict__ out, int* __restrict__ bsum)
{
  const int t = threadIdx.x, b = blockIdx.x;
  const int idx = b * 4096 + t * 16;
  int v[16];
  int s = 0;
  if (idx < TOTC) {
#pragma unroll
    for (int q = 0; q < 4; ++q) {
      const int4 qq = *(const int4*)(in + idx + q * 4);
      v[q * 4 + 0] = s; s += qq.x;
      v[q * 4 + 1] = s; s += qq.y;
      v[q * 4 + 2] = s; s += qq.z;
      v[q * 4 + 3] = s; s += qq.w;
    }
  } else {
    for (int j = 0; j < 16; ++j) v[j] = 0;
  }
  __shared__ int sh[256];
  sh[t] = s;
  __syncthreads();
  for (int d = 1; d < 256; d <<= 1) {
    const int u = (t >= d) ? sh[t - d] : 0;
    __syncthreads();
    sh[t] += u;
    __syncthreads();
  }
  const int excl = (t == 0) ? 0 : sh[t - 1];
  if (idx < TOTC) {
#pragma unroll
    for (int q = 0; q < 4; ++q) {
      int4 qo;
      qo.x = excl + v[q * 4 + 0]; qo.y = excl + v[q * 4 + 1];
      qo.z = excl + v[q * 4 + 2]; qo.w = excl + v[q * 4 + 3];
      *(int4*)(out + idx + q * 4) = qo;
    }
  }
  if (t == 255) bsum[b] = sh[255];
}

// ---------- shared logits2 body (rows [rbase, rbase + ...)) ----------
__device__ __forceinline__ void logits2_body(float (*lds)[16][148], int blk, int rbase,
    const short* __restrict__ A, const short* __restrict__ Bsd, const short* __restrict__ Bds,
    u16* __restrict__ hs, float* __restrict__ aSsd, float* __restrict__ aDsd,
    u16* __restrict__ hd, float* __restrict__ aSds, float* __restrict__ aDds, int M)
{
  const int t = threadIdx.x;
  const int wv = t >> 6, lane = t & 63;
  const int quad = lane >> 4, l16 = lane & 15;
  const int row0 = rbase + blk * 64 + wv * 16;
  const int arow = min(row0 + l16, M - 1);
  const short* ap = A + (size_t)arow * 128 + quad * 8;
  bf16x8 af[4];
  for (int ks = 0; ks < 4; ++ks) af[ks] = *(const bf16x8*)(ap + ks * 32);
  const int row = row0 + l16;
  const int idx = lane & 7, rr = lane >> 3;
  for (int pass = 0; pass < 2; ++pass) {
    const short* B = pass ? Bds : Bsd;
    u16* outb = pass ? hd : hs;
    float* aS = pass ? aSds : aSsd;
    float* aD = pass ? aDds : aDsd;
    f32x4 acc[9];
    for (int ti = 0; ti < 9; ++ti) acc[ti] = (f32x4){0.f, 0.f, 0.f, 0.f};
    for (int ks = 0; ks < 4; ++ks)
      for (int ti = 0; ti < 9; ++ti) {
        const bf16x8 bf = *(const bf16x8*)(B + ((ti * 4 + ks) * 64 + lane) * 8);
        acc[ti] = __builtin_amdgcn_mfma_f32_16x16x32_bf16(af[ks], bf, acc[ti], 0, 0, 0);
      }
    for (int ti = 0; ti < 9; ++ti)
      for (int r = 0; r < 4; ++r)
        lds[wv][quad * 4 + r][ti * 16 + l16] = acc[ti][r];
    __syncthreads();
    if (row < M) {
      for (int g = 0; g < 8; ++g) {
        const f32x4 v = *(const f32x4*)&lds[wv][l16][g * 16 + quad * 4];
        uint2 pk;
        pk.x = (u32)f2bf(v[0]) | ((u32)f2bf(v[1]) << 16);
        pk.y = (u32)f2bf(v[2]) | ((u32)f2bf(v[3]) << 16);
        *(uint2*)(outb + (size_t)row * 128 + g * 16 + quad * 4) = pk;
      }
    }
    for (int p = 0; p < 2; ++p) {
      const int lr = p * 8 + rr;
      const int n = row0 + lr;
      if (n < M) {
        const float v = lds[wv][lr][128 + idx];
        if (idx < 4) aS[(size_t)n * 4 + idx] = v;
        else aD[(size_t)n * 4 + idx - 4] = v;
      }
    }
    __syncthreads();
  }
}

// ---------- K_C1: bin (256 blocks) ∪ logits2 rows [0, 50048) ----------
__global__ __launch_bounds__(256) void bin_logits2_kernel(
    const int* __restrict__ tt_src, const int* __restrict__ tt_dst,
    const int* __restrict__ ect_s, const int* __restrict__ ect_d,
    const int* __restrict__ scanned, const int* __restrict__ bsum, u32* __restrict__ bin,
    const short* __restrict__ A, const short* __restrict__ Bsd, const short* __restrict__ Bds,
    u16* __restrict__ hs, float* __restrict__ aSsd, float* __restrict__ aDsd,
    u16* __restrict__ hd, float* __restrict__ aSds, float* __restrict__ aDds, int M)
{
  __shared__ __align__(16) float ldsf[4][16][148];
  const int t = threadIdx.x;

  if (blockIdx.x < NBLK) {
    // ---------------- bin path ----------------
    int* cur = (int*)&ldsf[0][0][0];        // 2346 ints
    int* s_bpre = cur + 3 * NBK;            // 256 ints
    compute_bpre(bsum, s_bpre);
    const int b = blockIdx.x;
    for (int i = t; i < 3 * NBK; i += 256) {
      const int idx = i * NBLK + b;
      cur[i] = scanned[idx] + s_bpre[idx >> 12];
    }
    __syncthreads();
    const int lo = b * CHT, hi = min(lo + CHT, ETT);
    for (int i = lo + t; i < hi; i += 256) {
      const int s = tt_src[i], d = tt_dst[i];
      int p = atomicAdd(&cur[d >> 7], 1);
      bin[p] = ((u32)(d & 127) << 17) | (u32)s;
      p = atomicAdd(&cur[NBK + (s >> 7)], 1);
      bin[p] = ((u32)(s & 127) << 17) | (u32)d;
    }
    const int lo2 = b * CHC, hi2 = min(lo2 + CHC, ECT);
    for (int i = lo2 + t; i < hi2; i += 256) {
      const int s = ect_s[i], d = ect_d[i];
      const int p = atomicAdd(&cur[2 * NBK + (d >> 7)], 1);
      bin[p] = ((u32)(d & 127) << 17) | (u32)s;
    }
    return;
  }
  logits2_body(ldsf, blockIdx.x - NBLK, 0, A, Bsd, Bds,
               hs, aSsd, aDsd, hd, aSds, aDds, M);
}

// ---------- K_C2: bucket_fill (2346 blocks) ∪ logits2 rows [50048, NT) ----------
__global__ __launch_bounds__(256) void fill_logits2_kernel(
    const int* __restrict__ scanned, const int* __restrict__ bsum, const u32* __restrict__ bin,
    int* __restrict__ offs, int* __restrict__ big_el,
    const short* __restrict__ A, const short* __restrict__ Bsd, const short* __restrict__ Bds,
    u16* __restrict__ hs, float* __restrict__ aSsd, float* __restrict__ aDsd,
    u16* __restrict__ hd, float* __restrict__ aSds, float* __restrict__ aDds, int M)
{
  __shared__ __align__(16) float ldsf[4][16][148];
  const int t = threadIdx.x;

  if (blockIdx.x < 3 * NBK) {
    // ---------------- fill path (carved from ldsf: 4736 ints = 18.9KB) ----------------
    int* base0 = (int*)&ldsf[0][0][0];
    int* s_cnt = base0;            // 128
    int* s_exc = base0 + 128;      // 128
    int* s_cur = base0 + 256;      // 128
    int* s_bpre = base0 + 384;     // 256
    int* s_el = base0 + 640;       // FILL_CAP
    compute_bpre(bsum, s_bpre);
    const int rel = blockIdx.x / NBK;
    const int bucket = blockIdx.x - rel * NBK;
    if (t < 128) s_cnt[t] = 0;
    const int bi = blockIdx.x * NBLK;
    const int base = scanned[bi] + s_bpre[bi >> 12];
    const int nxt = (blockIdx.x == 3 * NBK - 1)
                        ? (2 * ETT + ECT)
                        : scanned[bi + NBLK] + s_bpre[(bi + NBLK) >> 12];
    __syncthreads();
    const int size = nxt - base;
    for (int i = t; i < size; i += 256)
      atomicAdd(&s_cnt[bin[base + i] >> 17], 1);
    __syncthreads();
    if (t < 128) s_exc[t] = s_cnt[t];
    __syncthreads();
    for (int d = 1; d < 128; d <<= 1) {
      int v = 0;
      if (t < 128 && t >= d) v = s_exc[t - d];
      __syncthreads();
      if (t < 128) s_exc[t] += v;
      __syncthreads();
    }
    const int relbase = rel * ETT;
    const int obase = base - relbase;
    int* off_rel = offs + (size_t)rel * OFFS;
    const int node0 = bucket * 128;
    if (t < 128) {
      const int excl = s_exc[t] - s_cnt[t];
      s_cur[t] = excl;                    // bucket-LOCAL cursor
      if (node0 + t < NT) off_rel[node0 + t] = obase + excl;
    }
    if (t == 0 && bucket == NBK - 1) off_rel[NT] = obase + size;
    __syncthreads();
    int* el_rel = big_el + relbase;
    if (size <= FILL_CAP) {
      for (int i = t; i < size; i += 256) {
        const u32 e = bin[base + i];
        const int pos = atomicAdd(&s_cur[e >> 17], 1);
        s_el[pos] = (int)(e & 0x1FFFFu);
      }
      __syncthreads();
      for (int i = t; i < size; i += 256)
        el_rel[obase + i] = s_el[i];
    } else {
      for (int i = t; i < size; i += 256) {
        const u32 e = bin[base + i];
        const int pos = atomicAdd(&s_cur[e >> 17], 1);
        el_rel[obase + pos] = (int)(e & 0x1FFFFu);
      }
    }
    return;
  }
  logits2_body(ldsf, blockIdx.x - 3 * NBK, GOH, A, Bsd, Bds,
               hs, aSsd, aDsd, hd, aSds, aDds, M);
}

// ---------- mfma_out body ----------
__device__ __forceinline__ void mfma_out_body(float (*lds)[16][132], int row0,
    const short* __restrict__ A, const short* __restrict__ B,
    const float* __restrict__ bias, float* __restrict__ out, int M)
{
  const int t = threadIdx.x;
  const int wv = t >> 6, lane = t & 63;
  const int quad = lane >> 4, l16 = lane & 15;
  const int r0 = row0 + wv * 16;
  const int arow = min(r0 + l16, M - 1);
  const short* ap = A + (size_t)arow * 128 + quad * 8;
  bf16x8 af[4];
  for (int ks = 0; ks < 4; ++ks) af[ks] = *(const bf16x8*)(ap + ks * 32);
  f32x4 acc[8];
  for (int ti = 0; ti < 8; ++ti) acc[ti] = (f32x4){0.f, 0.f, 0.f, 0.f};
  for (int ks = 0; ks < 4; ++ks)
    for (int ti = 0; ti < 8; ++ti) {
      const bf16x8 bf = *(const bf16x8*)(B + ((ti * 4 + ks) * 64 + lane) * 8);
      acc[ti] = __builtin_amdgcn_mfma_f32_16x16x32_bf16(af[ks], bf, acc[ti], 0, 0, 0);
    }
  for (int ti = 0; ti < 8; ++ti)
    for (int r = 0; r < 4; ++r)
      lds[wv][quad * 4 + r][ti * 16 + l16] = acc[ti][r];
  __syncthreads();
  const int row = r0 + l16;
  if (row < M) {
    for (int g = 0; g < 8; ++g) {
      const int col = g * 16 + quad * 4;
      f32x4 v = *(const f32x4*)&lds[wv][l16][col];
      const f32x4 b4 = *(const f32x4*)(bias + col);
      v = v + b4;
      *(f32x4*)(out + (size_t)row * 128 + col) = v;
    }
  }
}

__global__ __launch_bounds__(256) void mfma_out_kernel(
    const short* __restrict__ A, const short* __restrict__ B,
    const float* __restrict__ bias, float* __restrict__ out, int rbase, int M)
{
  __shared__ __align__(16) float lds[4][16][132];
  mfma_out_body(lds, rbase + blockIdx.x * 64, A, B, bias, out, M);
}

// ---------- gather pipeline (R0 depth-1, exp2f; structural roofline ~3.5TB/s) ----------
__device__ __forceinline__ void gat_pipe16(const int* __restrict__ off,
    const int* __restrict__ el, const float* __restrict__ aS, const float* __restrict__ aD,
    const u16* __restrict__ hb, int d, int h, int cb, int self_loop, float w,
    float* __restrict__ acc)
{
  const float ad = aD[(size_t)d * 4 + h];
  const int beg = off[d];
  const int m = off[d + 1] - beg;     // real edges
  const int cnt = m + self_loop;
  if (cnt <= 0) return;
  float den = 0.f;
  float a0 = 0.f, a1 = 0.f, a2 = 0.f, a3 = 0.f, a4 = 0.f, a5 = 0.f, a6 = 0.f, a7 = 0.f;
  int sB = (1 < m) ? el[beg + 1] : d;
  {
    const int sA0 = (0 < m) ? el[beg] : d;
    float eA = aS[(size_t)sA0 * 4 + h];
    uint4 pA = *(const uint4*)(hb + (size_t)sA0 * 128 + cb);
    for (int k = 0; k < cnt; ++k) {
      const int sC = (k + 2 < m) ? el[beg + k + 2] : d;
      const float eB = aS[(size_t)sB * 4 + h];
      const uint4 pB = *(const uint4*)(hb + (size_t)sB * 128 + cb);
      float ea = eA + ad;
      ea = ea > 0.f ? ea : SLOPE * ea;
      const float ex = exp2f(ea);
      den += ex;
      a0 = fmaf(ex, lof(pA.x), a0); a1 = fmaf(ex, hif(pA.x), a1);
      a2 = fmaf(ex, lof(pA.y), a2); a3 = fmaf(ex, hif(pA.y), a3);
      a4 = fmaf(ex, lof(pA.z), a4); a5 = fmaf(ex, hif(pA.z), a5);
      a6 = fmaf(ex, lof(pA.w), a6); a7 = fmaf(ex, hif(pA.w), a7);
      eA = eB; pA = pB; sB = sC;
    }
  }
  const float s = w / den;
  acc[0] = fmaf(a0, s, acc[0]); acc[1] = fmaf(a1, s, acc[1]);
  acc[2] = fmaf(a2, s, acc[2]); acc[3] = fmaf(a3, s, acc[3]);
  acc[4] = fmaf(a4, s, acc[4]); acc[5] = fmaf(a5, s, acc[5]);
  acc[6] = fmaf(a6, s, acc[6]); acc[7] = fmaf(a7, s, acc[7]);
}

__device__ __forceinline__ void gather_body(int d,
    const int* __restrict__ off_f, const int* __restrict__ el_f,
    const float* __restrict__ aS_sd, const float* __restrict__ aD_sd, const u16* __restrict__ hs,
    const int* __restrict__ off_r, const int* __restrict__ el_r,
    const float* __restrict__ aS_ds, const float* __restrict__ aD_ds, const u16* __restrict__ hd,
    const int* __restrict__ off_c, const int* __restrict__ el_c,
    const float* __restrict__ aS_ct, const float* __restrict__ aD_ct, const u16* __restrict__ hc,
    const u16* __restrict__ skip, const float* __restrict__ cbias, u16* __restrict__ x)
{
  const int lg = threadIdx.x & 15;
  const int h = lg >> 2;
  const int cb = lg * 8;
  float acc[8];
  for (int i = 0; i < 8; ++i) acc[i] = 0.f;
  gat_pipe16(off_f, el_f, aS_sd, aD_sd, hs, d, h, cb, 1, 0.25f, acc);
  gat_pipe16(off_r, el_r, aS_ds, aD_ds, hd, d, h, cb, 1, 0.25f, acc);
  gat_pipe16(off_c, el_c, aS_ct, aD_ct, hc, d, h, cb, 0, 0.5f, acc);
  const uint4 sk = *(const uint4*)(skip + (size_t)d * 128 + cb);
  const float4 cb0 = *(const float4*)(cbias + cb);
  const float4 cb1 = *(const float4*)(cbias + cb + 4);
  const float o0 = fmaxf(acc[0] + cb0.x + lof(sk.x), 0.f);
  const float o1 = fmaxf(acc[1] + cb0.y + hif(sk.x), 0.f);
  const float o2 = fmaxf(acc[2] + cb0.z + lof(sk.y), 0.f);
  const float o3 = fmaxf(acc[3] + cb0.w + hif(sk.y), 0.f);
  const float o4 = fmaxf(acc[4] + cb1.x + lof(sk.z), 0.f);
  const float o5 = fmaxf(acc[5] + cb1.y + hif(sk.z), 0.f);
  const float o6 = fmaxf(acc[6] + cb1.z + lof(sk.w), 0.f);
  const float o7 = fmaxf(acc[7] + cb1.w + hif(sk.w), 0.f);
  uint4 r;
  r.x = (u32)f2bf(o0) | ((u32)f2bf(o1) << 16);
  r.y = (u32)f2bf(o2) | ((u32)f2bf(o3) << 16);
  r.z = (u32)f2bf(o4) | ((u32)f2bf(o5) << 16);
  r.w = (u32)f2bf(o6) | ((u32)f2bf(o7) << 16);
  *(uint4*)(x + (size_t)d * 128 + cb) = r;
}

// gather stage 1: dst < GOH
__global__ __launch_bounds__(256) void gather_all_kernel(
    const int* __restrict__ off_f, const int* __restrict__ el_f,
    const float* __restrict__ aS_sd, const float* __restrict__ aD_sd, const u16* __restrict__ hs,
    const int* __restrict__ off_r, const int* __restrict__ el_r,
    const float* __restrict__ aS_ds, const float* __restrict__ aD_ds, const u16* __restrict__ hd,
    const int* __restrict__ off_c, const int* __restrict__ el_c,
    const float* __restrict__ aS_ct, const float* __restrict__ aD_ct, const u16* __restrict__ hc,
    const u16* __restrict__ skip, const float* __restrict__ cbias, u16* __restrict__ x)
{
  const int d = blockIdx.x * 16 + (threadIdx.x >> 4);
  if (d >= NT) return;
  gather_body(d, off_f, el_f, aS_sd, aD_sd, hs, off_r, el_r, aS_ds, aD_ds, hd,
              off_c, el_c, aS_ct, aD_ct, hc, skip, cbias, x);
}

// gather stage 2 (dst >= GOH) ∪ mfma_out rows [0, GOH)
__global__ __launch_bounds__(256) void gather_out_kernel(
    const int* __restrict__ off_f, const int* __restrict__ el_f,
    const float* __restrict__ aS_sd, const float* __restrict__ aD_sd, const u16* __restrict__ hs,
    const int* __restrict__ off_r, const int* __restrict__ el_r,
    const float* __restrict__ aS_ds, const float* __restrict__ aD_ds, const u16* __restrict__ hd,
    const int* __restrict__ off_c, const int* __restrict__ el_c,
    const float* __restrict__ aS_ct, const float* __restrict__ aD_ct, const u16* __restrict__ hc,
    const u16* __restrict__ skip, const float* __restrict__ cbias, u16* __restrict__ x,
    const short* __restrict__ B, const float* __restrict__ bias, float* __restrict__ out, int M)
{
  __shared__ __align__(16) float lds[4][16][132];
  if (blockIdx.x < G2BLK) {
    const int d = GOH + blockIdx.x * 16 + (threadIdx.x >> 4);
    if (d >= NT) return;
    gather_body(d, off_f, el_f, aS_sd, aD_sd, hs, off_r, el_r, aS_ds, aD_ds, hd,
                off_c, el_c, aS_ct, aD_ct, hc, skip, cbias, x);
    return;
  }
  mfma_out_body(lds, (blockIdx.x - G2BLK) * 64, (const short*)x, B, bias, out, M);
}

extern "C" void kernel_launch(void* const* d_in, const int* in_sizes, int n_in,
                              void* d_out, int out_size, void* d_ws, size_t ws_size,
                              hipStream_t stream)
{
  const float* x_t   = (const float*)d_in[0];
  const float* x_c   = (const float*)d_in[1];
  const int*   e_tt  = (const int*)d_in[2];
  const int*   ect_s = (const int*)d_in[3];
  const int*   ect_d = (const int*)d_in[4];
  const float* Wpt = (const float*)d_in[5];   const float* bpt = (const float*)d_in[6];
  const float* Wpc = (const float*)d_in[7];   const float* bpc = (const float*)d_in[8];
  const float* Wsd = (const float*)d_in[9];   const float* As_sd = (const float*)d_in[10];
  const float* Ad_sd = (const float*)d_in[11]; const float* bsd = (const float*)d_in[12];
  const float* Wds = (const float*)d_in[13];  const float* As_ds = (const float*)d_in[14];
  const float* Ad_ds = (const float*)d_in[15]; const float* bds = (const float*)d_in[16];
  const float* Wcs = (const float*)d_in[17];  const float* Wcd = (const float*)d_in[18];
  const float* As_ct = (const float*)d_in[19]; const float* Ad_ct = (const float*)d_in[20];
  const float* bct = (const float*)d_in[21];
  const float* Wout = (const float*)d_in[22]; const float* bout = (const float*)d_in[23];

  // workspace
  char* p = (char*)d_ws;
  size_t off = 0;
  auto alloc = [&](size_t bytes) { char* r = p + off; off += (bytes + 255) & ~(size_t)255; return r; };
  u16* ht_bf   = (u16*)alloc((size_t)NT * 128 * 2);
  u16* hs_bf   = (u16*)alloc((size_t)NT * 128 * 2);
  u16* hd_bf   = (u16*)alloc((size_t)NT * 128 * 2);
  u16* hc_bf   = (u16*)alloc((size_t)NC * 128 * 2);
  u16* x_bf    = (u16*)alloc((size_t)NT * 128 * 2);
  float* aS_sd = (float*)alloc((size_t)NT * 4 * 4);
  float* aD_sd = (float*)alloc((size_t)NT * 4 * 4);
  float* aS_ds = (float*)alloc((size_t)NT * 4 * 4);
  float* aD_ds = (float*)alloc((size_t)NT * 4 * 4);
  float* aS_ct = (float*)alloc((size_t)NC * 4 * 4);
  float* aD_ct = (float*)alloc((size_t)NT * 4 * 4);
  int* cntblk  = (int*)alloc((size_t)TOTC * 4);
  int* scanned = (int*)alloc((size_t)TOTC * 4);
  u32* bin     = (u32*)alloc((size_t)(2 * ETT + ECT) * 4);
  int* big_el  = (int*)alloc((size_t)(2 * ETT + ECT) * 4);
  int* offs    = (int*)alloc((size_t)3 * OFFS * 4);
  int* bsum    = (int*)alloc((size_t)NSB * 4);
  float* cbias   = (float*)alloc(128 * 4);
  u16* bfrag_sd  = (u16*)alloc((size_t)9 * 4 * 64 * 8 * 2);
  u16* bfrag_ds  = (u16*)alloc((size_t)9 * 4 * 64 * 8 * 2);
  u16* bfrag_out = (u16*)alloc((size_t)8 * 4 * 64 * 8 * 2);

  int* off_f = offs;
  int* off_r = offs + OFFS;
  int* off_c = offs + 2 * OFFS;
  int* el_f = big_el;
  int* el_r = big_el + ETT;
  int* el_c = big_el + 2 * ETT;

  const int* tt_src = e_tt;
  const int* tt_dst = e_tt + ETT;

  // K_A: hist ∪ prep ∪ pre_t ∪ ctx
  transform_hist_kernel<<<NBLK + 4 + PT_BLK + CT_BLK, 256, 0, stream>>>(
      tt_src, tt_dst, ect_d, cntblk,
      Wsd, As_sd, Ad_sd, Wds, As_ds, Ad_ds, Wout,
      bfrag_sd, bfrag_ds, bfrag_out,
      Wcd, Ad_ct, bsd, bds, bct, cbias,
      x_t, Wpt, bpt, ht_bf, aD_ct,
      x_c, Wpc, bpc, Wcs, As_ct, hc_bf, aS_ct);

  // scan
  scan2_blk_kernel<<<NSB, 256, 0, stream>>>(cntblk, scanned, bsum);

  // K_C1: bin ∪ logits2 rows [0, GOH)
  bin_logits2_kernel<<<NBLK + LROWS1, 256, 0, stream>>>(
      tt_src, tt_dst, ect_s, ect_d, scanned, bsum, bin,
      (const short*)ht_bf, (const short*)bfrag_sd, (const short*)bfrag_ds,
      hs_bf, aS_sd, aD_sd, hd_bf, aS_ds, aD_ds, NT);

  // K_C2: bucket_fill ∪ logits2 rows [GOH, NT)
  fill_logits2_kernel<<<3 * NBK + LROWS2, 256, 0, stream>>>(
      scanned, bsum, bin, offs, big_el,
      (const short*)ht_bf, (const short*)bfrag_sd, (const short*)bfrag_ds,
      hs_bf, aS_sd, aD_sd, hd_bf, aS_ds, aD_ds, NT);

  // gather stage 1: dst < GOH
  gather_all_kernel<<<G1BLK, 256, 0, stream>>>(
      off_f, el_f, aS_sd, aD_sd, hs_bf,
      off_r, el_r, aS_ds, aD_ds, hd_bf,
      off_c, el_c, aS_ct, aD_ct, hc_bf,
      ht_bf, cbias, x_bf);

  // gather stage 2 (dst >= GOH) ∪ mfma_out rows [0, GOH)
  gather_out_kernel<<<G2BLK + OB1, 256, 0, stream>>>(
      off_f, el_f, aS_sd, aD_sd, hs_bf,
      off_r, el_r, aS_ds, aD_ds, hd_bf,
      off_c, el_c, aS_ct, aD_ct, hc_bf,
      ht_bf, cbias, x_bf,
      (const short*)bfrag_out, bout, (float*)d_out, NT);

  // mfma_out rows [GOH, NT)
  mfma_out_kernel<<<OB2, 256, 0, stream>>>((const short*)x_bf, (const short*)bfrag_out,
                                           bout, (float*)d_out, GOH, NT);
}

// Round 10
// 389.160 us; speedup vs baseline: 1.2767x; 1.0528x over previous
//
#include <hip/hip_runtime.h>
#include <cstdint>
#include <cstddef>

typedef unsigned short u16;
typedef unsigned int u32;

#define NT 100000
#define NC 25000
#define ETT 800000
#define ECT 400000
#define SLOPE 0.2f
#define LOG2E 1.4426950408889634f
#define OFFS (NT + 4)           // padded stride for offset arrays (16B-aligned)

// bucket-binned CSR build (R6 design: block-exclusive bin sub-segments keep
// dirty lines XCD-local; R7's global scatter had 20x HBM write amplification)
#define NBK 782                 // ceil(NT/128) buckets of 128 nodes
#define NBLK 256                // binning blocks
#define CHT ((ETT + NBLK - 1) / NBLK)   // 3125 tt edges / block
#define CHC ((ECT + NBLK - 1) / NBLK)   // 1563 ct edges / block
#define TOTC (3 * NBK * NBLK)           // 600576 counts
#define NSB ((TOTC + 4095) / 4096)      // 147 scan blocks
#define FILL_CAP 4096                   // LDS staging capacity for bucket_fill (ints)

#define PT_BLK ((NT + 63) / 64)   // 1563 pre_t blocks (64 rows each)
#define CT_BLK ((NC + 63) / 64)   // 391 ctx blocks
#define GM_BLK ((NT + 63) / 64)   // 1563 logits2 blocks (full, R6 structure)

// gather/out pipeline: stage2 gather fused with ZERO-LDS mfma_out (R9 lesson:
// fusing an LDS-heavy path into a latency-bound kernel taxes every block's
// occupancy -- LDS is allocated per-kernel, not per-branch)
#define GOH 50048                       // split point (782*64, /16 exact)
#define G1BLK (GOH / 16)                // 3128 gather blocks, dst < GOH
#define G2BLK ((NT - GOH) / 16)         // 3122 gather blocks, dst >= GOH (exact)
#define OB1 (GOH / 64)                  // 782 out blocks, rows < GOH
#define OB2 ((NT - GOH + 63) / 64)      // 781 out blocks, rows >= GOH

typedef __attribute__((ext_vector_type(8))) short bf16x8;
typedef __attribute__((ext_vector_type(4))) float f32x4;

__device__ __forceinline__ u16 f2bf(float f) {
  u32 u = __float_as_uint(f);
  u32 r = (u >> 16) & 1u;
  return (u16)((u + 0x7fffu + r) >> 16);
}
__device__ __forceinline__ float lof(u32 p) { return __uint_as_float(p << 16); }
__device__ __forceinline__ float hif(u32 p) { return __uint_as_float(p & 0xffff0000u); }

// exclusive prefix of bsum[0..NSB) into s_bpre[0..256)
__device__ __forceinline__ void compute_bpre(const int* __restrict__ bsum, int* s_bpre) {
  const int t = threadIdx.x;
  const int v = (t < NSB) ? bsum[t] : 0;
  s_bpre[t] = v;
  __syncthreads();
  for (int d = 1; d < 256; d <<= 1) {
    const int u = (t >= d) ? s_bpre[t - d] : 0;
    __syncthreads();
    s_bpre[t] += u;
    __syncthreads();
  }
  const int incl = s_bpre[t];
  __syncthreads();
  s_bpre[t] = incl - v;
  __syncthreads();
}

// ---------- K_A: hist (256) ∪ prep (4) ∪ pre_t (1563) ∪ ctx (391) ----------
__global__ __launch_bounds__(256) void transform_hist_kernel(
    const int* __restrict__ tt_src, const int* __restrict__ tt_dst,
    const int* __restrict__ ect_d, int* __restrict__ cntblk,
    const float* __restrict__ Wsd, const float* __restrict__ AsSd, const float* __restrict__ AdSd,
    const float* __restrict__ Wds, const float* __restrict__ AsDs, const float* __restrict__ AdDs,
    const float* __restrict__ Wout,
    u16* __restrict__ bf_sd, u16* __restrict__ bf_ds, u16* __restrict__ bf_out,
    const float* __restrict__ Wcd, const float* __restrict__ attD,
    const float* __restrict__ bsd, const float* __restrict__ bds, const float* __restrict__ bct,
    float* __restrict__ cbias,
    const float* __restrict__ x_t, const float* __restrict__ Wpt, const float* __restrict__ bpt,
    u16* __restrict__ h_t, float* __restrict__ aD,
    const float* __restrict__ x_c, const float* __restrict__ Wpc, const float* __restrict__ bpc,
    const float* __restrict__ Wcs, const float* __restrict__ attS,
    u16* __restrict__ hc_bf, float* __restrict__ aS_c)
{
  __shared__ __align__(16) char smem[51200];
  const int t = threadIdx.x;

  if (blockIdx.x < NBLK) {
    // ---------------- hist path ----------------
    int* h = (int*)smem;               // 2346 ints
    const int b = blockIdx.x;
    for (int i = t; i < 3 * NBK; i += 256) h[i] = 0;
    __syncthreads();
    const int lo = b * CHT, hi = min(lo + CHT, ETT);
    for (int i = lo + t; i < hi; i += 256) {
      atomicAdd(&h[tt_dst[i] >> 7], 1);
      atomicAdd(&h[NBK + (tt_src[i] >> 7)], 1);
    }
    const int lo2 = b * CHC, hi2 = min(lo2 + CHC, ECT);
    for (int i = lo2 + t; i < hi2; i += 256)
      atomicAdd(&h[2 * NBK + (ect_d[i] >> 7)], 1);
    __syncthreads();
    for (int i = t; i < 3 * NBK; i += 256)
      cntblk[(size_t)i * NBLK + b] = h[i];
    return;
  }

  const int b = blockIdx.x - NBLK;

  if (b < 4) {
    // ---------------- prep path ----------------
    if (b == 3) {
      if (t < 128) cbias[t] = 0.25f * bsd[t] + 0.25f * bds[t] + 0.5f * bct[t];
      return;
    }
    float* fS = (float*)smem;
    float* fD = fS + 512;
    const float* W = (b == 0) ? Wsd : (b == 1) ? Wds : Wout;
    const float* As = (b == 0) ? AsSd : AsDs;
    const float* Ad = (b == 0) ? AdSd : AdDs;
    u16* out = (b == 0) ? bf_sd : (b == 1) ? bf_ds : bf_out;
    const int tiles = (b == 2) ? 8 : 9;
    if (b < 2) {
      if (t < 128) {
        for (int hh = 0; hh < 4; ++hh) {
          float s1 = 0.f, s2 = 0.f;
          for (int c = 0; c < 32; ++c) {
            const float wv = W[t * 128 + hh * 32 + c];
            s1 = fmaf(wv, As[hh * 32 + c], s1);
            s2 = fmaf(wv, Ad[hh * 32 + c], s2);
          }
          fS[t * 4 + hh] = s1 * LOG2E; fD[t * 4 + hh] = s2 * LOG2E;
        }
      }
      __syncthreads();
    }
    const int total = tiles * 4 * 64 * 8;
    for (int i = t; i < total; i += 256) {
      const int j = i & 7, lane = (i >> 3) & 63, ks = (i >> 9) & 3, ti = i >> 11;
      const int k = ks * 32 + (lane >> 4) * 8 + j;
      const int n = ti * 16 + (lane & 15);
      float v;
      if (n < 128) v = W[k * 128 + n];
      else if (n < 132) v = fS[k * 4 + (n - 128)];
      else if (n < 136) v = fD[k * 4 + (n - 132)];
      else v = 0.f;
      out[i] = f2bf(v);
    }
    return;
  }

  if (b < 4 + PT_BLK) {
    // ---------------- pre_t path (64 rows/block, 4r x 8c / thread) ----------------
    float (*s_xt)[68] = (float(*)[68])smem;                 // 64 x 68 x4 = 17408
    float (*s_W)[128] = (float(*)[128])(smem + 17408);      // 32 x 128 x4 = 16384
    float* s_fold     = (float*)(smem + 17408 + 16384);     // 512 x4 = 2048
    const int row0 = (b - 4) * 64;
    for (int g = 0; g < 4; ++g) {
      const int lr = g * 16 + (t >> 4);
      const int k4 = (t & 15) * 4;
      const int grow = row0 + lr;
      float4 f = make_float4(0.f, 0.f, 0.f, 0.f);
      if (grow < NT) f = *(const float4*)(x_t + (size_t)grow * 64 + k4);
      s_xt[k4 + 0][lr] = f.x; s_xt[k4 + 1][lr] = f.y;
      s_xt[k4 + 2][lr] = f.z; s_xt[k4 + 3][lr] = f.w;
    }
    if (t < 128) {
      for (int hh = 0; hh < 4; ++hh) {
        float s = 0.f;
        for (int c = 0; c < 32; ++c)
          s = fmaf(Wcd[t * 128 + hh * 32 + c], attD[hh * 32 + c], s);
        s_fold[t * 4 + hh] = s * LOG2E;
      }
    }
    const int rg = t >> 4;        // row group
    const int cg = t & 15;        // col groups cg*4 and cg*4+64
    float acc[4][8];
    for (int r = 0; r < 4; ++r)
      for (int j = 0; j < 8; ++j)
        acc[r][j] = bpt[cg * 4 + (j & 3) + (j >> 2) * 64];
    for (int kc = 0; kc < 64; kc += 32) {
      for (int j = 0; j < 4; ++j) {
        const int idx = t + j * 256;
        const int k = idx >> 5, c4 = (idx & 31) * 4;
        *(float4*)&s_W[k][c4] = *(const float4*)(Wpt + (size_t)(kc + k) * 128 + c4);
      }
      __syncthreads();
#pragma unroll 8
      for (int k = 0; k < 32; ++k) {
        const float4 xa = *(const float4*)&s_xt[kc + k][rg * 4];
        const float4 w0 = *(const float4*)&s_W[k][cg * 4];
        const float4 w1 = *(const float4*)&s_W[k][cg * 4 + 64];
        const float xr[4] = {xa.x, xa.y, xa.z, xa.w};
        for (int r = 0; r < 4; ++r) {
          acc[r][0] = fmaf(xr[r], w0.x, acc[r][0]);
          acc[r][1] = fmaf(xr[r], w0.y, acc[r][1]);
          acc[r][2] = fmaf(xr[r], w0.z, acc[r][2]);
          acc[r][3] = fmaf(xr[r], w0.w, acc[r][3]);
          acc[r][4] = fmaf(xr[r], w1.x, acc[r][4]);
          acc[r][5] = fmaf(xr[r], w1.y, acc[r][5]);
          acc[r][6] = fmaf(xr[r], w1.z, acc[r][6]);
          acc[r][7] = fmaf(xr[r], w1.w, acc[r][7]);
        }
      }
      __syncthreads();
    }
    for (int r = 0; r < 4; ++r) {
      const int grow = row0 + rg * 4 + r;
      float v[8];
      for (int j = 0; j < 8; ++j) v[j] = fmaxf(acc[r][j], 0.f);
      float p0 = 0.f, p1 = 0.f, p2 = 0.f, p3 = 0.f;
      for (int j = 0; j < 8; ++j) {
        const int col = cg * 4 + (j & 3) + ((j >> 2) * 64);
        const float4 f4 = *(const float4*)&s_fold[col * 4];
        p0 = fmaf(v[j], f4.x, p0); p1 = fmaf(v[j], f4.y, p1);
        p2 = fmaf(v[j], f4.z, p2); p3 = fmaf(v[j], f4.w, p3);
      }
      if (grow < NT) {
        uint2 pk;
        pk.x = (u32)f2bf(v[0]) | ((u32)f2bf(v[1]) << 16);
        pk.y = (u32)f2bf(v[2]) | ((u32)f2bf(v[3]) << 16);
        *(uint2*)(h_t + (size_t)grow * 128 + cg * 4) = pk;
        pk.x = (u32)f2bf(v[4]) | ((u32)f2bf(v[5]) << 16);
        pk.y = (u32)f2bf(v[6]) | ((u32)f2bf(v[7]) << 16);
        *(uint2*)(h_t + (size_t)grow * 128 + cg * 4 + 64) = pk;
      }
      for (int m = 1; m < 16; m <<= 1) {
        p0 += __shfl_xor(p0, m); p1 += __shfl_xor(p1, m);
        p2 += __shfl_xor(p2, m); p3 += __shfl_xor(p3, m);
      }
      if (cg == 0 && grow < NT)
        *(float4*)(aD + (size_t)grow * 4) = make_float4(p0, p1, p2, p3);
    }
    return;
  }

  // ---------------- ctx path (64 rows/block, 4r x 8c / thread) ----------------
  {
    float (*s_ht)[68]  = (float(*)[68])smem;                // 128 x 68 x4 = 34816
    float (*s_W2)[128] = (float(*)[128])(smem + 34816);     // 16384 (total 51200)
    float (*s_xc)[68]  = (float(*)[68])smem;                // alias: dead before s_ht writes
    const int row0 = (b - 4 - PT_BLK) * 64;
    for (int g = 0; g < 2; ++g) {
      const int lr = g * 32 + (t >> 3);
      const int k4 = (t & 7) * 4;
      const int grow = row0 + lr;
      float4 f = make_float4(0.f, 0.f, 0.f, 0.f);
      if (grow < NC) f = *(const float4*)(x_c + (size_t)grow * 32 + k4);
      s_xc[k4 + 0][lr] = f.x; s_xc[k4 + 1][lr] = f.y;
      s_xc[k4 + 2][lr] = f.z; s_xc[k4 + 3][lr] = f.w;
    }
    for (int j = 0; j < 4; ++j) {
      const int idx = t + j * 256;
      const int k = idx >> 5, c4 = (idx & 31) * 4;
      *(float4*)&s_W2[k][c4] = *(const float4*)(Wpc + (size_t)k * 128 + c4);
    }
    __syncthreads();
    const int rg = t >> 4, cg = t & 15;
    float acc1[4][8];
    for (int r = 0; r < 4; ++r)
      for (int j = 0; j < 8; ++j)
        acc1[r][j] = bpc[cg * 4 + (j & 3) + (j >> 2) * 64];
#pragma unroll 8
    for (int k = 0; k < 32; ++k) {
      const float4 xa = *(const float4*)&s_xc[k][rg * 4];
      const float4 w0 = *(const float4*)&s_W2[k][cg * 4];
      const float4 w1 = *(const float4*)&s_W2[k][cg * 4 + 64];
      const float xr[4] = {xa.x, xa.y, xa.z, xa.w};
      for (int r = 0; r < 4; ++r) {
        acc1[r][0] = fmaf(xr[r], w0.x, acc1[r][0]);
        acc1[r][1] = fmaf(xr[r], w0.y, acc1[r][1]);
        acc1[r][2] = fmaf(xr[r], w0.z, acc1[r][2]);
        acc1[r][3] = fmaf(xr[r], w0.w, acc1[r][3]);
        acc1[r][4] = fmaf(xr[r], w1.x, acc1[r][4]);
        acc1[r][5] = fmaf(xr[r], w1.y, acc1[r][5]);
        acc1[r][6] = fmaf(xr[r], w1.z, acc1[r][6]);
        acc1[r][7] = fmaf(xr[r], w1.w, acc1[r][7]);
      }
    }
    __syncthreads();                 // s_xc dead
    for (int r = 0; r < 4; ++r) {
      const int lr = rg * 4 + r;
      for (int j = 0; j < 8; ++j) {
        const int col = cg * 4 + (j & 3) + ((j >> 2) * 64);
        s_ht[col][lr] = fmaxf(acc1[r][j], 0.f);
      }
    }
    for (int j = 0; j < 4; ++j) {
      const int idx = t + j * 256;
      const int k = idx >> 5, c4 = (idx & 31) * 4;
      *(float4*)&s_W2[k][c4] = *(const float4*)(Wcs + (size_t)k * 128 + c4);
    }
    __syncthreads();
    float acc2[4][8];
    for (int r = 0; r < 4; ++r)
      for (int j = 0; j < 8; ++j) acc2[r][j] = 0.f;
    for (int kc = 0; kc < 128; kc += 32) {
#pragma unroll 8
      for (int k = 0; k < 32; ++k) {
        const float4 xa = *(const float4*)&s_ht[kc + k][rg * 4];
        const float4 w0 = *(const float4*)&s_W2[k][cg * 4];
        const float4 w1 = *(const float4*)&s_W2[k][cg * 4 + 64];
        const float xr[4] = {xa.x, xa.y, xa.z, xa.w};
        for (int r = 0; r < 4; ++r) {
          acc2[r][0] = fmaf(xr[r], w0.x, acc2[r][0]);
          acc2[r][1] = fmaf(xr[r], w0.y, acc2[r][1]);
          acc2[r][2] = fmaf(xr[r], w0.z, acc2[r][2]);
          acc2[r][3] = fmaf(xr[r], w0.w, acc2[r][3]);
          acc2[r][4] = fmaf(xr[r], w1.x, acc2[r][4]);
          acc2[r][5] = fmaf(xr[r], w1.y, acc2[r][5]);
          acc2[r][6] = fmaf(xr[r], w1.z, acc2[r][6]);
          acc2[r][7] = fmaf(xr[r], w1.w, acc2[r][7]);
        }
      }
      if (kc < 96) {
        __syncthreads();
        for (int j = 0; j < 4; ++j) {
          const int idx = t + j * 256;
          const int k = idx >> 5, c4 = (idx & 31) * 4;
          *(float4*)&s_W2[k][c4] = *(const float4*)(Wcs + (size_t)(kc + 32 + k) * 128 + c4);
        }
        __syncthreads();
      }
    }
    const int h2 = cg >> 3;
    const float4 at0 = *(const float4*)(attS + cg * 4);
    const float4 at1 = *(const float4*)(attS + cg * 4 + 64);
    for (int r = 0; r < 4; ++r) {
      const int grow = row0 + rg * 4 + r;
      float pa = acc2[r][0] * at0.x + acc2[r][1] * at0.y +
                 acc2[r][2] * at0.z + acc2[r][3] * at0.w;
      float pb = acc2[r][4] * at1.x + acc2[r][5] * at1.y +
                 acc2[r][6] * at1.z + acc2[r][7] * at1.w;
      if (grow < NC) {
        uint2 pk;
        pk.x = (u32)f2bf(acc2[r][0]) | ((u32)f2bf(acc2[r][1]) << 16);
        pk.y = (u32)f2bf(acc2[r][2]) | ((u32)f2bf(acc2[r][3]) << 16);
        *(uint2*)(hc_bf + (size_t)grow * 128 + cg * 4) = pk;
        pk.x = (u32)f2bf(acc2[r][4]) | ((u32)f2bf(acc2[r][5]) << 16);
        pk.y = (u32)f2bf(acc2[r][6]) | ((u32)f2bf(acc2[r][7]) << 16);
        *(uint2*)(hc_bf + (size_t)grow * 128 + cg * 4 + 64) = pk;
      }
      for (int m = 1; m < 8; m <<= 1) {
        pa += __shfl_xor(pa, m);
        pb += __shfl_xor(pb, m);
      }
      if ((cg & 7) == 0 && grow < NC) {
        aS_c[(size_t)grow * 4 + h2] = pa * LOG2E;
        aS_c[(size_t)grow * 4 + 2 + h2] = pb * LOG2E;
      }
    }
  }
}

// ---------- scan2_blk: 4096-chunk exclusive scan (partial) + chunk totals ----------
__global__ __launch_bounds__(256) void scan2_blk_kernel(const int* __restrict__ in,
    int* __restrict__ out, int* __restrict__ bsum)
{
  const int t = threadIdx.x, b = blockIdx.x;
  const int idx = b * 4096 + t * 16;
  int v[16];
  int s = 0;
  if (idx < TOTC) {
#pragma unroll
    for (int q = 0; q < 4; ++q) {
      const int4 qq = *(const int4*)(in + idx + q * 4);
      v[q * 4 + 0] = s; s += qq.x;
      v[q * 4 + 1] = s; s += qq.y;
      v[q * 4 + 2] = s; s += qq.z;
      v[q * 4 + 3] = s; s += qq.w;
    }
  } else {
    for (int j = 0; j < 16; ++j) v[j] = 0;
  }
  __shared__ int sh[256];
  sh[t] = s;
  __syncthreads();
  for (int d = 1; d < 256; d <<= 1) {
    const int u = (t >= d) ? sh[t - d] : 0;
    __syncthreads();
    sh[t] += u;
    __syncthreads();
  }
  const int excl = (t == 0) ? 0 : sh[t - 1];
  if (idx < TOTC) {
#pragma unroll
    for (int q = 0; q < 4; ++q) {
      int4 qo;
      qo.x = excl + v[q * 4 + 0]; qo.y = excl + v[q * 4 + 1];
      qo.z = excl + v[q * 4 + 2]; qo.w = excl + v[q * 4 + 3];
      *(int4*)(out + idx + q * 4) = qo;
    }
  }
  if (t == 255) bsum[b] = sh[255];
}

// ---------- shared logits2 body ----------
__device__ __forceinline__ void logits2_body(float (*lds)[16][148], int blk,
    const short* __restrict__ A, const short* __restrict__ Bsd, const short* __restrict__ Bds,
    u16* __restrict__ hs, float* __restrict__ aSsd, float* __restrict__ aDsd,
    u16* __restrict__ hd, float* __restrict__ aSds, float* __restrict__ aDds, int M)
{
  const int t = threadIdx.x;
  const int wv = t >> 6, lane = t & 63;
  const int quad = lane >> 4, l16 = lane & 15;
  const int row0 = blk * 64 + wv * 16;
  const int arow = min(row0 + l16, M - 1);
  const short* ap = A + (size_t)arow * 128 + quad * 8;
  bf16x8 af[4];
  for (int ks = 0; ks < 4; ++ks) af[ks] = *(const bf16x8*)(ap + ks * 32);
  const int row = row0 + l16;
  const int idx = lane & 7, rr = lane >> 3;
  for (int pass = 0; pass < 2; ++pass) {
    const short* B = pass ? Bds : Bsd;
    u16* outb = pass ? hd : hs;
    float* aS = pass ? aSds : aSsd;
    float* aD = pass ? aDds : aDsd;
    f32x4 acc[9];
    for (int ti = 0; ti < 9; ++ti) acc[ti] = (f32x4){0.f, 0.f, 0.f, 0.f};
    for (int ks = 0; ks < 4; ++ks)
      for (int ti = 0; ti < 9; ++ti) {
        const bf16x8 bf = *(const bf16x8*)(B + ((ti * 4 + ks) * 64 + lane) * 8);
        acc[ti] = __builtin_amdgcn_mfma_f32_16x16x32_bf16(af[ks], bf, acc[ti], 0, 0, 0);
      }
    for (int ti = 0; ti < 9; ++ti)
      for (int r = 0; r < 4; ++r)
        lds[wv][quad * 4 + r][ti * 16 + l16] = acc[ti][r];
    __syncthreads();
    if (row < M) {
      for (int g = 0; g < 8; ++g) {
        const f32x4 v = *(const f32x4*)&lds[wv][l16][g * 16 + quad * 4];
        uint2 pk;
        pk.x = (u32)f2bf(v[0]) | ((u32)f2bf(v[1]) << 16);
        pk.y = (u32)f2bf(v[2]) | ((u32)f2bf(v[3]) << 16);
        *(uint2*)(outb + (size_t)row * 128 + g * 16 + quad * 4) = pk;
      }
    }
    for (int p = 0; p < 2; ++p) {
      const int lr = p * 8 + rr;
      const int n = row0 + lr;
      if (n < M) {
        const float v = lds[wv][lr][128 + idx];
        if (idx < 4) aS[(size_t)n * 4 + idx] = v;
        else aD[(size_t)n * 4 + idx - 4] = v;
      }
    }
    __syncthreads();
  }
}

// ---------- K_C: bin (256 blocks) ∪ logits2 (1563 blocks, full -- R6 structure) ----------
__global__ __launch_bounds__(256) void bin_logits2_kernel(
    const int* __restrict__ tt_src, const int* __restrict__ tt_dst,
    const int* __restrict__ ect_s, const int* __restrict__ ect_d,
    const int* __restrict__ scanned, const int* __restrict__ bsum, u32* __restrict__ bin,
    const short* __restrict__ A, const short* __restrict__ Bsd, const short* __restrict__ Bds,
    u16* __restrict__ hs, float* __restrict__ aSsd, float* __restrict__ aDsd,
    u16* __restrict__ hd, float* __restrict__ aSds, float* __restrict__ aDds, int M)
{
  __shared__ __align__(16) float ldsf[4][16][148];
  const int t = threadIdx.x;

  if (blockIdx.x < NBLK) {
    // ---------------- bin path ----------------
    int* cur = (int*)&ldsf[0][0][0];        // 2346 ints
    int* s_bpre = cur + 3 * NBK;            // 256 ints
    compute_bpre(bsum, s_bpre);
    const int b = blockIdx.x;
    for (int i = t; i < 3 * NBK; i += 256) {
      const int idx = i * NBLK + b;
      cur[i] = scanned[idx] + s_bpre[idx >> 12];
    }
    __syncthreads();
    const int lo = b * CHT, hi = min(lo + CHT, ETT);
    for (int i = lo + t; i < hi; i += 256) {
      const int s = tt_src[i], d = tt_dst[i];
      int p = atomicAdd(&cur[d >> 7], 1);
      bin[p] = ((u32)(d & 127) << 17) | (u32)s;
      p = atomicAdd(&cur[NBK + (s >> 7)], 1);
      bin[p] = ((u32)(s & 127) << 17) | (u32)d;
    }
    const int lo2 = b * CHC, hi2 = min(lo2 + CHC, ECT);
    for (int i = lo2 + t; i < hi2; i += 256) {
      const int s = ect_s[i], d = ect_d[i];
      const int p = atomicAdd(&cur[2 * NBK + (d >> 7)], 1);
      bin[p] = ((u32)(d & 127) << 17) | (u32)s;
    }
    return;
  }
  logits2_body(ldsf, blockIdx.x - NBLK, A, Bsd, Bds,
               hs, aSsd, aDsd, hd, aSds, aDds, M);
}

// ---------- bucket_fill: standalone, small LDS (R6 structure) ----------
__global__ __launch_bounds__(256) void bucket_fill_kernel(const int* __restrict__ scanned,
    const int* __restrict__ bsum, const u32* __restrict__ bin,
    int* __restrict__ offs, int* __restrict__ big_el)
{
  __shared__ int s_cnt[128], s_exc[128], s_cur[128], s_bpre[256];
  __shared__ int s_el[FILL_CAP];
  const int t = threadIdx.x;
  compute_bpre(bsum, s_bpre);
  const int rel = blockIdx.x / NBK;
  const int bucket = blockIdx.x - rel * NBK;
  if (t < 128) s_cnt[t] = 0;
  const int bi = blockIdx.x * NBLK;
  const int base = scanned[bi] + s_bpre[bi >> 12];
  const int nxt = (blockIdx.x == 3 * NBK - 1)
                      ? (2 * ETT + ECT)
                      : scanned[bi + NBLK] + s_bpre[(bi + NBLK) >> 12];
  __syncthreads();
  const int size = nxt - base;
  for (int i = t; i < size; i += 256)
    atomicAdd(&s_cnt[bin[base + i] >> 17], 1);
  __syncthreads();
  if (t < 128) s_exc[t] = s_cnt[t];
  __syncthreads();
  for (int d = 1; d < 128; d <<= 1) {
    int v = 0;
    if (t < 128 && t >= d) v = s_exc[t - d];
    __syncthreads();
    if (t < 128) s_exc[t] += v;
    __syncthreads();
  }
  const int relbase = rel * ETT;
  const int obase = base - relbase;
  int* off_rel = offs + (size_t)rel * OFFS;
  const int node0 = bucket * 128;
  if (t < 128) {
    const int excl = s_exc[t] - s_cnt[t];
    s_cur[t] = excl;                    // bucket-LOCAL cursor
    if (node0 + t < NT) off_rel[node0 + t] = obase + excl;
  }
  if (t == 0 && bucket == NBK - 1) off_rel[NT] = obase + size;
  __syncthreads();
  int* el_rel = big_el + relbase;
  if (size <= FILL_CAP) {
    for (int i = t; i < size; i += 256) {
      const u32 e = bin[base + i];
      const int pos = atomicAdd(&s_cur[e >> 17], 1);
      s_el[pos] = (int)(e & 0x1FFFFu);
    }
    __syncthreads();
    for (int i = t; i < size; i += 256)
      el_rel[obase + i] = s_el[i];
  } else {
    for (int i = t; i < size; i += 256) {
      const u32 e = bin[base + i];
      const int pos = atomicAdd(&s_cur[e >> 17], 1);
      el_rel[obase + pos] = (int)(e & 0x1FFFFu);
    }
  }
}

// ---------- mfma_out, ZERO-LDS: direct fragment-layout stores ----------
// C/D layout for mfma_f32_16x16x32_bf16: col=lane&15, row=(lane>>4)*4+reg
// (learn_hip m89). acc[ti][r] = C[quad*4+r][ti*16+l16] -> write directly:
// 16 l16-lanes store 64B-contiguous runs per (ti,quad,r). Bitwise identical
// to the LDS-transpose version; LDS=0 so fusion doesn't tax gather occupancy.
__device__ __forceinline__ void mfma_out_direct(int row0,
    const short* __restrict__ A, const short* __restrict__ B,
    const float* __restrict__ bias, float* __restrict__ out, int M)
{
  const int t = threadIdx.x;
  const int wv = t >> 6, lane = t & 63;
  const int quad = lane >> 4, l16 = lane & 15;
  const int r0 = row0 + wv * 16;
  const int arow = min(r0 + l16, M - 1);
  const short* ap = A + (size_t)arow * 128 + quad * 8;
  bf16x8 af[4];
  for (int ks = 0; ks < 4; ++ks) af[ks] = *(const bf16x8*)(ap + ks * 32);
  f32x4 acc[8];
  for (int ti = 0; ti < 8; ++ti) acc[ti] = (f32x4){0.f, 0.f, 0.f, 0.f};
  for (int ks = 0; ks < 4; ++ks)
    for (int ti = 0; ti < 8; ++ti) {
      const bf16x8 bf = *(const bf16x8*)(B + ((ti * 4 + ks) * 64 + lane) * 8);
      acc[ti] = __builtin_amdgcn_mfma_f32_16x16x32_bf16(af[ks], bf, acc[ti], 0, 0, 0);
    }
  float bcol[8];
#pragma unroll
  for (int ti = 0; ti < 8; ++ti) bcol[ti] = bias[ti * 16 + l16];
#pragma unroll
  for (int r = 0; r < 4; ++r) {
    const int row = r0 + quad * 4 + r;
    if (row < M) {
      float* orow = out + (size_t)row * 128 + l16;
#pragma unroll
      for (int ti = 0; ti < 8; ++ti)
        orow[ti * 16] = acc[ti][r] + bcol[ti];
    }
  }
}

__global__ __launch_bounds__(256) void mfma_out_kernel(
    const short* __restrict__ A, const short* __restrict__ B,
    const float* __restrict__ bias, float* __restrict__ out, int rbase, int M)
{
  mfma_out_direct(rbase + blockIdx.x * 64, A, B, bias, out, M);
}

// ---------- gather pipeline (R0 depth-1, exp2f; structural roofline ~3.5TB/s) ----------
__device__ __forceinline__ void gat_pipe16(const int* __restrict__ off,
    const int* __restrict__ el, const float* __restrict__ aS, const float* __restrict__ aD,
    const u16* __restrict__ hb, int d, int h, int cb, int self_loop, float w,
    float* __restrict__ acc)
{
  const float ad = aD[(size_t)d * 4 + h];
  const int beg = off[d];
  const int m = off[d + 1] - beg;     // real edges
  const int cnt = m + self_loop;
  if (cnt <= 0) return;
  float den = 0.f;
  float a0 = 0.f, a1 = 0.f, a2 = 0.f, a3 = 0.f, a4 = 0.f, a5 = 0.f, a6 = 0.f, a7 = 0.f;
  int sB = (1 < m) ? el[beg + 1] : d;
  {
    const int sA0 = (0 < m) ? el[beg] : d;
    float eA = aS[(size_t)sA0 * 4 + h];
    uint4 pA = *(const uint4*)(hb + (size_t)sA0 * 128 + cb);
    for (int k = 0; k < cnt; ++k) {
      const int sC = (k + 2 < m) ? el[beg + k + 2] : d;
      const float eB = aS[(size_t)sB * 4 + h];
      const uint4 pB = *(const uint4*)(hb + (size_t)sB * 128 + cb);
      float ea = eA + ad;
      ea = ea > 0.f ? ea : SLOPE * ea;
      const float ex = exp2f(ea);
      den += ex;
      a0 = fmaf(ex, lof(pA.x), a0); a1 = fmaf(ex, hif(pA.x), a1);
      a2 = fmaf(ex, lof(pA.y), a2); a3 = fmaf(ex, hif(pA.y), a3);
      a4 = fmaf(ex, lof(pA.z), a4); a5 = fmaf(ex, hif(pA.z), a5);
      a6 = fmaf(ex, lof(pA.w), a6); a7 = fmaf(ex, hif(pA.w), a7);
      eA = eB; pA = pB; sB = sC;
    }
  }
  const float s = w / den;
  acc[0] = fmaf(a0, s, acc[0]); acc[1] = fmaf(a1, s, acc[1]);
  acc[2] = fmaf(a2, s, acc[2]); acc[3] = fmaf(a3, s, acc[3]);
  acc[4] = fmaf(a4, s, acc[4]); acc[5] = fmaf(a5, s, acc[5]);
  acc[6] = fmaf(a6, s, acc[6]); acc[7] = fmaf(a7, s, acc[7]);
}

__device__ __forceinline__ void gather_body(int d,
    const int* __restrict__ off_f, const int* __restrict__ el_f,
    const float* __restrict__ aS_sd, const float* __restrict__ aD_sd, const u16* __restrict__ hs,
    const int* __restrict__ off_r, const int* __restrict__ el_r,
    const float* __restrict__ aS_ds, const float* __restrict__ aD_ds, const u16* __restrict__ hd,
    const int* __restrict__ off_c, const int* __restrict__ el_c,
    const float* __restrict__ aS_ct, const float* __restrict__ aD_ct, const u16* __restrict__ hc,
    const u16* __restrict__ skip, const float* __restrict__ cbias, u16* __restrict__ x)
{
  const int lg = threadIdx.x & 15;
  const int h = lg >> 2;
  const int cb = lg * 8;
  float acc[8];
  for (int i = 0; i < 8; ++i) acc[i] = 0.f;
  gat_pipe16(off_f, el_f, aS_sd, aD_sd, hs, d, h, cb, 1, 0.25f, acc);
  gat_pipe16(off_r, el_r, aS_ds, aD_ds, hd, d, h, cb, 1, 0.25f, acc);
  gat_pipe16(off_c, el_c, aS_ct, aD_ct, hc, d, h, cb, 0, 0.5f, acc);
  const uint4 sk = *(const uint4*)(skip + (size_t)d * 128 + cb);
  const float4 cb0 = *(const float4*)(cbias + cb);
  const float4 cb1 = *(const float4*)(cbias + cb + 4);
  const float o0 = fmaxf(acc[0] + cb0.x + lof(sk.x), 0.f);
  const float o1 = fmaxf(acc[1] + cb0.y + hif(sk.x), 0.f);
  const float o2 = fmaxf(acc[2] + cb0.z + lof(sk.y), 0.f);
  const float o3 = fmaxf(acc[3] + cb0.w + hif(sk.y), 0.f);
  const float o4 = fmaxf(acc[4] + cb1.x + lof(sk.z), 0.f);
  const float o5 = fmaxf(acc[5] + cb1.y + hif(sk.z), 0.f);
  const float o6 = fmaxf(acc[6] + cb1.z + lof(sk.w), 0.f);
  const float o7 = fmaxf(acc[7] + cb1.w + hif(sk.w), 0.f);
  uint4 r;
  r.x = (u32)f2bf(o0) | ((u32)f2bf(o1) << 16);
  r.y = (u32)f2bf(o2) | ((u32)f2bf(o3) << 16);
  r.z = (u32)f2bf(o4) | ((u32)f2bf(o5) << 16);
  r.w = (u32)f2bf(o6) | ((u32)f2bf(o7) << 16);
  *(uint4*)(x + (size_t)d * 128 + cb) = r;
}

// gather stage 1: dst < GOH
__global__ __launch_bounds__(256) void gather_all_kernel(
    const int* __restrict__ off_f, const int* __restrict__ el_f,
    const float* __restrict__ aS_sd, const float* __restrict__ aD_sd, const u16* __restrict__ hs,
    const int* __restrict__ off_r, const int* __restrict__ el_r,
    const float* __restrict__ aS_ds, const float* __restrict__ aD_ds, const u16* __restrict__ hd,
    const int* __restrict__ off_c, const int* __restrict__ el_c,
    const float* __restrict__ aS_ct, const float* __restrict__ aD_ct, const u16* __restrict__ hc,
    const u16* __restrict__ skip, const float* __restrict__ cbias, u16* __restrict__ x)
{
  const int d = blockIdx.x * 16 + (threadIdx.x >> 4);
  if (d >= NT) return;
  gather_body(d, off_f, el_f, aS_sd, aD_sd, hs, off_r, el_r, aS_ds, aD_ds, hd,
              off_c, el_c, aS_ct, aD_ct, hc, skip, cbias, x);
}

// gather stage 2 (dst >= GOH) ∪ mfma_out rows [0, GOH) -- NO shared memory
__global__ __launch_bounds__(256) void gather_out_kernel(
    const int* __restrict__ off_f, const int* __restrict__ el_f,
    const float* __restrict__ aS_sd, const float* __restrict__ aD_sd, const u16* __restrict__ hs,
    const int* __restrict__ off_r, const int* __restrict__ el_r,
    const float* __restrict__ aS_ds, const float* __restrict__ aD_ds, const u16* __restrict__ hd,
    const int* __restrict__ off_c, const int* __restrict__ el_c,
    const float* __restrict__ aS_ct, const float* __restrict__ aD_ct, const u16* __restrict__ hc,
    const u16* __restrict__ skip, const float* __restrict__ cbias, u16* __restrict__ x,
    const short* __restrict__ B, const float* __restrict__ bias, float* __restrict__ out, int M)
{
  if (blockIdx.x < G2BLK) {
    const int d = GOH + blockIdx.x * 16 + (threadIdx.x >> 4);
    if (d >= NT) return;
    gather_body(d, off_f, el_f, aS_sd, aD_sd, hs, off_r, el_r, aS_ds, aD_ds, hd,
                off_c, el_c, aS_ct, aD_ct, hc, skip, cbias, x);
    return;
  }
  mfma_out_direct((blockIdx.x - G2BLK) * 64, (const short*)x, B, bias, out, M);
}

extern "C" void kernel_launch(void* const* d_in, const int* in_sizes, int n_in,
                              void* d_out, int out_size, void* d_ws, size_t ws_size,
                              hipStream_t stream)
{
  const float* x_t   = (const float*)d_in[0];
  const float* x_c   = (const float*)d_in[1];
  const int*   e_tt  = (const int*)d_in[2];
  const int*   ect_s = (const int*)d_in[3];
  const int*   ect_d = (const int*)d_in[4];
  const float* Wpt = (const float*)d_in[5];   const float* bpt = (const float*)d_in[6];
  const float* Wpc = (const float*)d_in[7];   const float* bpc = (const float*)d_in[8];
  const float* Wsd = (const float*)d_in[9];   const float* As_sd = (const float*)d_in[10];
  const float* Ad_sd = (const float*)d_in[11]; const float* bsd = (const float*)d_in[12];
  const float* Wds = (const float*)d_in[13];  const float* As_ds = (const float*)d_in[14];
  const float* Ad_ds = (const float*)d_in[15]; const float* bds = (const float*)d_in[16];
  const float* Wcs = (const float*)d_in[17];  const float* Wcd = (const float*)d_in[18];
  const float* As_ct = (const float*)d_in[19]; const float* Ad_ct = (const float*)d_in[20];
  const float* bct = (const float*)d_in[21];
  const float* Wout = (const float*)d_in[22]; const float* bout = (const float*)d_in[23];

  // workspace
  char* p = (char*)d_ws;
  size_t off = 0;
  auto alloc = [&](size_t bytes) { char* r = p + off; off += (bytes + 255) & ~(size_t)255; return r; };
  u16* ht_bf   = (u16*)alloc((size_t)NT * 128 * 2);
  u16* hs_bf   = (u16*)alloc((size_t)NT * 128 * 2);
  u16* hd_bf   = (u16*)alloc((size_t)NT * 128 * 2);
  u16* hc_bf   = (u16*)alloc((size_t)NC * 128 * 2);
  u16* x_bf    = (u16*)alloc((size_t)NT * 128 * 2);
  float* aS_sd = (float*)alloc((size_t)NT * 4 * 4);
  float* aD_sd = (float*)alloc((size_t)NT * 4 * 4);
  float* aS_ds = (float*)alloc((size_t)NT * 4 * 4);
  float* aD_ds = (float*)alloc((size_t)NT * 4 * 4);
  float* aS_ct = (float*)alloc((size_t)NC * 4 * 4);
  float* aD_ct = (float*)alloc((size_t)NT * 4 * 4);
  int* cntblk  = (int*)alloc((size_t)TOTC * 4);
  int* scanned = (int*)alloc((size_t)TOTC * 4);
  u32* bin     = (u32*)alloc((size_t)(2 * ETT + ECT) * 4);
  int* big_el  = (int*)alloc((size_t)(2 * ETT + ECT) * 4);
  int* offs    = (int*)alloc((size_t)3 * OFFS * 4);
  int* bsum    = (int*)alloc((size_t)NSB * 4);
  float* cbias   = (float*)alloc(128 * 4);
  u16* bfrag_sd  = (u16*)alloc((size_t)9 * 4 * 64 * 8 * 2);
  u16* bfrag_ds  = (u16*)alloc((size_t)9 * 4 * 64 * 8 * 2);
  u16* bfrag_out = (u16*)alloc((size_t)8 * 4 * 64 * 8 * 2);

  int* off_f = offs;
  int* off_r = offs + OFFS;
  int* off_c = offs + 2 * OFFS;
  int* el_f = big_el;
  int* el_r = big_el + ETT;
  int* el_c = big_el + 2 * ETT;

  const int* tt_src = e_tt;
  const int* tt_dst = e_tt + ETT;

  // K_A: hist ∪ prep ∪ pre_t ∪ ctx
  transform_hist_kernel<<<NBLK + 4 + PT_BLK + CT_BLK, 256, 0, stream>>>(
      tt_src, tt_dst, ect_d, cntblk,
      Wsd, As_sd, Ad_sd, Wds, As_ds, Ad_ds, Wout,
      bfrag_sd, bfrag_ds, bfrag_out,
      Wcd, Ad_ct, bsd, bds, bct, cbias,
      x_t, Wpt, bpt, ht_bf, aD_ct,
      x_c, Wpc, bpc, Wcs, As_ct, hc_bf, aS_ct);

  // scan
  scan2_blk_kernel<<<NSB, 256, 0, stream>>>(cntblk, scanned, bsum);

  // K_C: bin ∪ logits2 (full, R6 structure)
  bin_logits2_kernel<<<NBLK + GM_BLK, 256, 0, stream>>>(
      tt_src, tt_dst, ect_s, ect_d, scanned, bsum, bin,
      (const short*)ht_bf, (const short*)bfrag_sd, (const short*)bfrag_ds,
      hs_bf, aS_sd, aD_sd, hd_bf, aS_ds, aD_ds, NT);

  // bucket_fill (standalone, small LDS)
  bucket_fill_kernel<<<3 * NBK, 256, 0, stream>>>(scanned, bsum, bin, offs, big_el);

  // gather stage 1: dst < GOH
  gather_all_kernel<<<G1BLK, 256, 0, stream>>>(
      off_f, el_f, aS_sd, aD_sd, hs_bf,
      off_r, el_r, aS_ds, aD_ds, hd_bf,
      off_c, el_c, aS_ct, aD_ct, hc_bf,
      ht_bf, cbias, x_bf);

  // gather stage 2 (dst >= GOH) ∪ mfma_out rows [0, GOH)  [zero-LDS fusion]
  gather_out_kernel<<<G2BLK + OB1, 256, 0, stream>>>(
      off_f, el_f, aS_sd, aD_sd, hs_bf,
      off_r, el_r, aS_ds, aD_ds, hd_bf,
      off_c, el_c, aS_ct, aD_ct, hc_bf,
      ht_bf, cbias, x_bf,
      (const short*)bfrag_out, bout, (float*)d_out, NT);

  // mfma_out rows [GOH, NT)
  mfma_out_kernel<<<OB2, 256, 0, stream>>>((const short*)x_bf, (const short*)bfrag_out,
                                           bout, (float*)d_out, GOH, NT);
}

// Round 11
// 381.874 us; speedup vs baseline: 1.3011x; 1.0191x over previous
//
#include <hip/hip_runtime.h>
#include <cstdint>
#include <cstddef>

typedef unsigned short u16;
typedef unsigned int u32;

#define NT 100000
#define NC 25000
#define ETT 800000
#define ECT 400000
#define SLOPE 0.2f
#define LOG2E 1.4426950408889634f
#define OFFS (NT + 4)           // padded stride for offset arrays (16B-aligned)

// bucket-binned CSR build (R6 design: block-exclusive bin sub-segments keep
// dirty lines XCD-local; R7's global scatter had 20x HBM write amplification)
#define NBK 782                 // ceil(NT/128) buckets of 128 nodes
#define NBLK 256                // binning blocks
#define CHT ((ETT + NBLK - 1) / NBLK)   // 3125 tt edges / block
#define CHC ((ECT + NBLK - 1) / NBLK)   // 1563 ct edges / block
#define TOTC (3 * NBK * NBLK)           // 600576 counts
#define NSB ((TOTC + 4095) / 4096)      // 147 scan blocks
#define FILL_CAP 4096                   // LDS staging capacity for bucket_fill (ints)

#define PT_BLK ((NT + 63) / 64)   // 1563 pre_t blocks (64 rows each)
#define CT_BLK ((NC + 31) / 32)   // 782 ctx blocks (32 rows each, R11: LDS<=27.6KB)
#define GM_BLK ((NT + 63) / 64)   // 1563 logits2 / mfma_out blocks

typedef __attribute__((ext_vector_type(8))) short bf16x8;
typedef __attribute__((ext_vector_type(4))) float f32x4;

__device__ __forceinline__ u16 f2bf(float f) {
  u32 u = __float_as_uint(f);
  u32 r = (u >> 16) & 1u;
  return (u16)((u + 0x7fffu + r) >> 16);
}
__device__ __forceinline__ float lof(u32 p) { return __uint_as_float(p << 16); }
__device__ __forceinline__ float hif(u32 p) { return __uint_as_float(p & 0xffff0000u); }

// exclusive prefix of bsum[0..NSB) into s_bpre[0..256)
__device__ __forceinline__ void compute_bpre(const int* __restrict__ bsum, int* s_bpre) {
  const int t = threadIdx.x;
  const int v = (t < NSB) ? bsum[t] : 0;
  s_bpre[t] = v;
  __syncthreads();
  for (int d = 1; d < 256; d <<= 1) {
    const int u = (t >= d) ? s_bpre[t - d] : 0;
    __syncthreads();
    s_bpre[t] += u;
    __syncthreads();
  }
  const int incl = s_bpre[t];
  __syncthreads();
  s_bpre[t] = incl - v;
  __syncthreads();
}

// ---------- K_A: hist (256) ∪ prep (4) ∪ pre_t (1563) ∪ ctx (782) ----------
// R11: every path fits in 27648B LDS -> 5 blocks/CU (was 51200B -> 3 blocks/CU,
// occupancy 26%, VALUBusy 32% -- transform was LDS-occupancy-bound at 84.8us).
// pre_t streams Wpt in [16][128] chunks; ctx moved to 32 rows/block with
// s_ht[128][36] + streamed W chunks. Inner-k accumulation order unchanged in
// both GEMMs -> h_t / hc_bf / logits bitwise identical.
__global__ __launch_bounds__(256) void transform_hist_kernel(
    const int* __restrict__ tt_src, const int* __restrict__ tt_dst,
    const int* __restrict__ ect_d, int* __restrict__ cntblk,
    const float* __restrict__ Wsd, const float* __restrict__ AsSd, const float* __restrict__ AdSd,
    const float* __restrict__ Wds, const float* __restrict__ AsDs, const float* __restrict__ AdDs,
    const float* __restrict__ Wout,
    u16* __restrict__ bf_sd, u16* __restrict__ bf_ds, u16* __restrict__ bf_out,
    const float* __restrict__ Wcd, const float* __restrict__ attD,
    const float* __restrict__ bsd, const float* __restrict__ bds, const float* __restrict__ bct,
    float* __restrict__ cbias,
    const float* __restrict__ x_t, const float* __restrict__ Wpt, const float* __restrict__ bpt,
    u16* __restrict__ h_t, float* __restrict__ aD,
    const float* __restrict__ x_c, const float* __restrict__ Wpc, const float* __restrict__ bpc,
    const float* __restrict__ Wcs, const float* __restrict__ attS,
    u16* __restrict__ hc_bf, float* __restrict__ aS_c)
{
  __shared__ __align__(16) char smem[27648];
  const int t = threadIdx.x;

  if (blockIdx.x < NBLK) {
    // ---------------- hist path (9384 B) ----------------
    int* h = (int*)smem;               // 2346 ints
    const int b = blockIdx.x;
    for (int i = t; i < 3 * NBK; i += 256) h[i] = 0;
    __syncthreads();
    const int lo = b * CHT, hi = min(lo + CHT, ETT);
    for (int i = lo + t; i < hi; i += 256) {
      atomicAdd(&h[tt_dst[i] >> 7], 1);
      atomicAdd(&h[NBK + (tt_src[i] >> 7)], 1);
    }
    const int lo2 = b * CHC, hi2 = min(lo2 + CHC, ECT);
    for (int i = lo2 + t; i < hi2; i += 256)
      atomicAdd(&h[2 * NBK + (ect_d[i] >> 7)], 1);
    __syncthreads();
    for (int i = t; i < 3 * NBK; i += 256)
      cntblk[(size_t)i * NBLK + b] = h[i];
    return;
  }

  const int b = blockIdx.x - NBLK;

  if (b < 4) {
    // ---------------- prep path (4096 B) ----------------
    if (b == 3) {
      if (t < 128) cbias[t] = 0.25f * bsd[t] + 0.25f * bds[t] + 0.5f * bct[t];
      return;
    }
    float* fS = (float*)smem;
    float* fD = fS + 512;
    const float* W = (b == 0) ? Wsd : (b == 1) ? Wds : Wout;
    const float* As = (b == 0) ? AsSd : AsDs;
    const float* Ad = (b == 0) ? AdSd : AdDs;
    u16* out = (b == 0) ? bf_sd : (b == 1) ? bf_ds : bf_out;
    const int tiles = (b == 2) ? 8 : 9;
    if (b < 2) {
      if (t < 128) {
        for (int hh = 0; hh < 4; ++hh) {
          float s1 = 0.f, s2 = 0.f;
          for (int c = 0; c < 32; ++c) {
            const float wv = W[t * 128 + hh * 32 + c];
            s1 = fmaf(wv, As[hh * 32 + c], s1);
            s2 = fmaf(wv, Ad[hh * 32 + c], s2);
          }
          fS[t * 4 + hh] = s1 * LOG2E; fD[t * 4 + hh] = s2 * LOG2E;
        }
      }
      __syncthreads();
    }
    const int total = tiles * 4 * 64 * 8;
    for (int i = t; i < total; i += 256) {
      const int j = i & 7, lane = (i >> 3) & 63, ks = (i >> 9) & 3, ti = i >> 11;
      const int k = ks * 32 + (lane >> 4) * 8 + j;
      const int n = ti * 16 + (lane & 15);
      float v;
      if (n < 128) v = W[k * 128 + n];
      else if (n < 132) v = fS[k * 4 + (n - 128)];
      else if (n < 136) v = fD[k * 4 + (n - 132)];
      else v = 0.f;
      out[i] = f2bf(v);
    }
    return;
  }

  if (b < 4 + PT_BLK) {
    // ---------------- pre_t path (64 rows, 4r x 8c / thread, 27648 B) ----------------
    float (*s_xt)[68] = (float(*)[68])smem;                 // 64 x 68 x4 = 17408
    float (*s_W)[128] = (float(*)[128])(smem + 17408);      // 16 x 128 x4 = 8192
    float* s_fold     = (float*)(smem + 17408 + 8192);      // 512 x4 = 2048
    const int row0 = (b - 4) * 64;
    for (int g = 0; g < 4; ++g) {
      const int lr = g * 16 + (t >> 4);
      const int k4 = (t & 15) * 4;
      const int grow = row0 + lr;
      float4 f = make_float4(0.f, 0.f, 0.f, 0.f);
      if (grow < NT) f = *(const float4*)(x_t + (size_t)grow * 64 + k4);
      s_xt[k4 + 0][lr] = f.x; s_xt[k4 + 1][lr] = f.y;
      s_xt[k4 + 2][lr] = f.z; s_xt[k4 + 3][lr] = f.w;
    }
    if (t < 128) {
      for (int hh = 0; hh < 4; ++hh) {
        float s = 0.f;
        for (int c = 0; c < 32; ++c)
          s = fmaf(Wcd[t * 128 + hh * 32 + c], attD[hh * 32 + c], s);
        s_fold[t * 4 + hh] = s * LOG2E;
      }
    }
    const int rg = t >> 4;        // row group
    const int cg = t & 15;        // col groups cg*4 and cg*4+64
    float acc[4][8];
    for (int r = 0; r < 4; ++r)
      for (int j = 0; j < 8; ++j)
        acc[r][j] = bpt[cg * 4 + (j & 3) + (j >> 2) * 64];
    for (int kc = 0; kc < 64; kc += 16) {
      for (int j = 0; j < 2; ++j) {
        const int idx = t + j * 256;
        const int k = idx >> 5, c4 = (idx & 31) * 4;
        *(float4*)&s_W[k][c4] = *(const float4*)(Wpt + (size_t)(kc + k) * 128 + c4);
      }
      __syncthreads();
#pragma unroll
      for (int k = 0; k < 16; ++k) {
        const float4 xa = *(const float4*)&s_xt[kc + k][rg * 4];
        const float4 w0 = *(const float4*)&s_W[k][cg * 4];
        const float4 w1 = *(const float4*)&s_W[k][cg * 4 + 64];
        const float xr[4] = {xa.x, xa.y, xa.z, xa.w};
        for (int r = 0; r < 4; ++r) {
          acc[r][0] = fmaf(xr[r], w0.x, acc[r][0]);
          acc[r][1] = fmaf(xr[r], w0.y, acc[r][1]);
          acc[r][2] = fmaf(xr[r], w0.z, acc[r][2]);
          acc[r][3] = fmaf(xr[r], w0.w, acc[r][3]);
          acc[r][4] = fmaf(xr[r], w1.x, acc[r][4]);
          acc[r][5] = fmaf(xr[r], w1.y, acc[r][5]);
          acc[r][6] = fmaf(xr[r], w1.z, acc[r][6]);
          acc[r][7] = fmaf(xr[r], w1.w, acc[r][7]);
        }
      }
      __syncthreads();
    }
    for (int r = 0; r < 4; ++r) {
      const int grow = row0 + rg * 4 + r;
      float v[8];
      for (int j = 0; j < 8; ++j) v[j] = fmaxf(acc[r][j], 0.f);
      float p0 = 0.f, p1 = 0.f, p2 = 0.f, p3 = 0.f;
      for (int j = 0; j < 8; ++j) {
        const int col = cg * 4 + (j & 3) + ((j >> 2) * 64);
        const float4 f4 = *(const float4*)&s_fold[col * 4];
        p0 = fmaf(v[j], f4.x, p0); p1 = fmaf(v[j], f4.y, p1);
        p2 = fmaf(v[j], f4.z, p2); p3 = fmaf(v[j], f4.w, p3);
      }
      if (grow < NT) {
        uint2 pk;
        pk.x = (u32)f2bf(v[0]) | ((u32)f2bf(v[1]) << 16);
        pk.y = (u32)f2bf(v[2]) | ((u32)f2bf(v[3]) << 16);
        *(uint2*)(h_t + (size_t)grow * 128 + cg * 4) = pk;
        pk.x = (u32)f2bf(v[4]) | ((u32)f2bf(v[5]) << 16);
        pk.y = (u32)f2bf(v[6]) | ((u32)f2bf(v[7]) << 16);
        *(uint2*)(h_t + (size_t)grow * 128 + cg * 4 + 64) = pk;
      }
      for (int m = 1; m < 16; m <<= 1) {
        p0 += __shfl_xor(p0, m); p1 += __shfl_xor(p1, m);
        p2 += __shfl_xor(p2, m); p3 += __shfl_xor(p3, m);
      }
      if (cg == 0 && grow < NT)
        *(float4*)(aD + (size_t)grow * 4) = make_float4(p0, p1, p2, p3);
    }
    return;
  }

  // ---------------- ctx path (32 rows, 2r x 8c / thread, 26624 B) ----------------
  {
    float (*s_ht)[36]  = (float(*)[36])smem;                // 128 x 36 x4 = 18432
    float (*s_W2)[128] = (float(*)[128])(smem + 18432);     // 16 x 128 x4 = 8192
    float (*s_xc)[36]  = (float(*)[36])smem;                // alias: 32x36 ⊂ s_ht, dead before s_ht writes
    const int row0 = (b - 4 - PT_BLK) * 32;
    {
      const int lr = t >> 3;            // 0..31
      const int k4 = (t & 7) * 4;       // 0..28
      const int grow = row0 + lr;
      float4 f = make_float4(0.f, 0.f, 0.f, 0.f);
      if (grow < NC) f = *(const float4*)(x_c + (size_t)grow * 32 + k4);
      s_xc[k4 + 0][lr] = f.x; s_xc[k4 + 1][lr] = f.y;
      s_xc[k4 + 2][lr] = f.z; s_xc[k4 + 3][lr] = f.w;
    }
    const int rg = t >> 4, cg = t & 15;
    float acc1[2][8];
    for (int r = 0; r < 2; ++r)
      for (int j = 0; j < 8; ++j)
        acc1[r][j] = bpc[cg * 4 + (j & 3) + (j >> 2) * 64];
    for (int kc = 0; kc < 32; kc += 16) {
      for (int j = 0; j < 2; ++j) {
        const int idx = t + j * 256;
        const int k = idx >> 5, c4 = (idx & 31) * 4;
        *(float4*)&s_W2[k][c4] = *(const float4*)(Wpc + (size_t)(kc + k) * 128 + c4);
      }
      __syncthreads();
#pragma unroll
      for (int k = 0; k < 16; ++k) {
        const float2 xa = *(const float2*)&s_xc[kc + k][rg * 2];
        const float4 w0 = *(const float4*)&s_W2[k][cg * 4];
        const float4 w1 = *(const float4*)&s_W2[k][cg * 4 + 64];
        const float xr[2] = {xa.x, xa.y};
        for (int r = 0; r < 2; ++r) {
          acc1[r][0] = fmaf(xr[r], w0.x, acc1[r][0]);
          acc1[r][1] = fmaf(xr[r], w0.y, acc1[r][1]);
          acc1[r][2] = fmaf(xr[r], w0.z, acc1[r][2]);
          acc1[r][3] = fmaf(xr[r], w0.w, acc1[r][3]);
          acc1[r][4] = fmaf(xr[r], w1.x, acc1[r][4]);
          acc1[r][5] = fmaf(xr[r], w1.y, acc1[r][5]);
          acc1[r][6] = fmaf(xr[r], w1.z, acc1[r][6]);
          acc1[r][7] = fmaf(xr[r], w1.w, acc1[r][7]);
        }
      }
      __syncthreads();                 // last iter: also fences s_xc before s_ht overwrite
    }
    // write relu(h) TRANSPOSED: s_ht[col][row]
    for (int r = 0; r < 2; ++r) {
      const int lr = rg * 2 + r;
      for (int j = 0; j < 8; ++j) {
        const int col = cg * 4 + (j & 3) + ((j >> 2) * 64);
        s_ht[col][lr] = fmaxf(acc1[r][j], 0.f);
      }
    }
    float acc2[2][8];
    for (int r = 0; r < 2; ++r)
      for (int j = 0; j < 8; ++j) acc2[r][j] = 0.f;
    for (int kc = 0; kc < 128; kc += 16) {
      for (int j = 0; j < 2; ++j) {
        const int idx = t + j * 256;
        const int k = idx >> 5, c4 = (idx & 31) * 4;
        *(float4*)&s_W2[k][c4] = *(const float4*)(Wcs + (size_t)(kc + k) * 128 + c4);
      }
      __syncthreads();                 // first iter: also fences s_ht writes
#pragma unroll
      for (int k = 0; k < 16; ++k) {
        const float2 xa = *(const float2*)&s_ht[kc + k][rg * 2];
        const float4 w0 = *(const float4*)&s_W2[k][cg * 4];
        const float4 w1 = *(const float4*)&s_W2[k][cg * 4 + 64];
        const float xr[2] = {xa.x, xa.y};
        for (int r = 0; r < 2; ++r) {
          acc2[r][0] = fmaf(xr[r], w0.x, acc2[r][0]);
          acc2[r][1] = fmaf(xr[r], w0.y, acc2[r][1]);
          acc2[r][2] = fmaf(xr[r], w0.z, acc2[r][2]);
          acc2[r][3] = fmaf(xr[r], w0.w, acc2[r][3]);
          acc2[r][4] = fmaf(xr[r], w1.x, acc2[r][4]);
          acc2[r][5] = fmaf(xr[r], w1.y, acc2[r][5]);
          acc2[r][6] = fmaf(xr[r], w1.z, acc2[r][6]);
          acc2[r][7] = fmaf(xr[r], w1.w, acc2[r][7]);
        }
      }
      __syncthreads();
    }
    const int h2 = cg >> 3;
    const float4 at0 = *(const float4*)(attS + cg * 4);
    const float4 at1 = *(const float4*)(attS + cg * 4 + 64);
    for (int r = 0; r < 2; ++r) {
      const int grow = row0 + rg * 2 + r;
      float pa = acc2[r][0] * at0.x + acc2[r][1] * at0.y +
                 acc2[r][2] * at0.z + acc2[r][3] * at0.w;
      float pb = acc2[r][4] * at1.x + acc2[r][5] * at1.y +
                 acc2[r][6] * at1.z + acc2[r][7] * at1.w;
      if (grow < NC) {
        uint2 pk;
        pk.x = (u32)f2bf(acc2[r][0]) | ((u32)f2bf(acc2[r][1]) << 16);
        pk.y = (u32)f2bf(acc2[r][2]) | ((u32)f2bf(acc2[r][3]) << 16);
        *(uint2*)(hc_bf + (size_t)grow * 128 + cg * 4) = pk;
        pk.x = (u32)f2bf(acc2[r][4]) | ((u32)f2bf(acc2[r][5]) << 16);
        pk.y = (u32)f2bf(acc2[r][6]) | ((u32)f2bf(acc2[r][7]) << 16);
        *(uint2*)(hc_bf + (size_t)grow * 128 + cg * 4 + 64) = pk;
      }
      for (int m = 1; m < 8; m <<= 1) {
        pa += __shfl_xor(pa, m);
        pb += __shfl_xor(pb, m);
      }
      if ((cg & 7) == 0 && grow < NC) {
        aS_c[(size_t)grow * 4 + h2] = pa * LOG2E;
        aS_c[(size_t)grow * 4 + 2 + h2] = pb * LOG2E;
      }
    }
  }
}

// ---------- scan2_blk: 4096-chunk exclusive scan (partial) + chunk totals ----------
__global__ __launch_bounds__(256) void scan2_blk_kernel(const int* __restrict__ in,
    int* __restrict__ out, int* __restrict__ bsum)
{
  const int t = threadIdx.x, b = blockIdx.x;
  const int idx = b * 4096 + t * 16;
  int v[16];
  int s = 0;
  if (idx < TOTC) {
#pragma unroll
    for (int q = 0; q < 4; ++q) {
      const int4 qq = *(const int4*)(in + idx + q * 4);
      v[q * 4 + 0] = s; s += qq.x;
      v[q * 4 + 1] = s; s += qq.y;
      v[q * 4 + 2] = s; s += qq.z;
      v[q * 4 + 3] = s; s += qq.w;
    }
  } else {
    for (int j = 0; j < 16; ++j) v[j] = 0;
  }
  __shared__ int sh[256];
  sh[t] = s;
  __syncthreads();
  for (int d = 1; d < 256; d <<= 1) {
    const int u = (t >= d) ? sh[t - d] : 0;
    __syncthreads();
    sh[t] += u;
    __syncthreads();
  }
  const int excl = (t == 0) ? 0 : sh[t - 1];
  if (idx < TOTC) {
#pragma unroll
    for (int q = 0; q < 4; ++q) {
      int4 qo;
      qo.x = excl + v[q * 4 + 0]; qo.y = excl + v[q * 4 + 1];
      qo.z = excl + v[q * 4 + 2]; qo.w = excl + v[q * 4 + 3];
      *(int4*)(out + idx + q * 4) = qo;
    }
  }
  if (t == 255) bsum[b] = sh[255];
}

// ---------- shared logits2 body ----------
__device__ __forceinline__ void logits2_body(float (*lds)[16][148], int blk,
    const short* __restrict__ A, const short* __restrict__ Bsd, const short* __restrict__ Bds,
    u16* __restrict__ hs, float* __restrict__ aSsd, float* __restrict__ aDsd,
    u16* __restrict__ hd, float* __restrict__ aSds, float* __restrict__ aDds, int M)
{
  const int t = threadIdx.x;
  const int wv = t >> 6, lane = t & 63;
  const int quad = lane >> 4, l16 = lane & 15;
  const int row0 = blk * 64 + wv * 16;
  const int arow = min(row0 + l16, M - 1);
  const short* ap = A + (size_t)arow * 128 + quad * 8;
  bf16x8 af[4];
  for (int ks = 0; ks < 4; ++ks) af[ks] = *(const bf16x8*)(ap + ks * 32);
  const int row = row0 + l16;
  const int idx = lane & 7, rr = lane >> 3;
  for (int pass = 0; pass < 2; ++pass) {
    const short* B = pass ? Bds : Bsd;
    u16* outb = pass ? hd : hs;
    float* aS = pass ? aSds : aSsd;
    float* aD = pass ? aDds : aDsd;
    f32x4 acc[9];
    for (int ti = 0; ti < 9; ++ti) acc[ti] = (f32x4){0.f, 0.f, 0.f, 0.f};
    for (int ks = 0; ks < 4; ++ks)
      for (int ti = 0; ti < 9; ++ti) {
        const bf16x8 bf = *(const bf16x8*)(B + ((ti * 4 + ks) * 64 + lane) * 8);
        acc[ti] = __builtin_amdgcn_mfma_f32_16x16x32_bf16(af[ks], bf, acc[ti], 0, 0, 0);
      }
    for (int ti = 0; ti < 9; ++ti)
      for (int r = 0; r < 4; ++r)
        lds[wv][quad * 4 + r][ti * 16 + l16] = acc[ti][r];
    __syncthreads();
    if (row < M) {
      for (int g = 0; g < 8; ++g) {
        const f32x4 v = *(const f32x4*)&lds[wv][l16][g * 16 + quad * 4];
        uint2 pk;
        pk.x = (u32)f2bf(v[0]) | ((u32)f2bf(v[1]) << 16);
        pk.y = (u32)f2bf(v[2]) | ((u32)f2bf(v[3]) << 16);
        *(uint2*)(outb + (size_t)row * 128 + g * 16 + quad * 4) = pk;
      }
    }
    for (int p = 0; p < 2; ++p) {
      const int lr = p * 8 + rr;
      const int n = row0 + lr;
      if (n < M) {
        const float v = lds[wv][lr][128 + idx];
        if (idx < 4) aS[(size_t)n * 4 + idx] = v;
        else aD[(size_t)n * 4 + idx - 4] = v;
      }
    }
    __syncthreads();
  }
}

// ---------- K_C: bin (256 blocks) ∪ logits2 (1563 blocks) ----------
__global__ __launch_bounds__(256) void bin_logits2_kernel(
    const int* __restrict__ tt_src, const int* __restrict__ tt_dst,
    const int* __restrict__ ect_s, const int* __restrict__ ect_d,
    const int* __restrict__ scanned, const int* __restrict__ bsum, u32* __restrict__ bin,
    const short* __restrict__ A, const short* __restrict__ Bsd, const short* __restrict__ Bds,
    u16* __restrict__ hs, float* __restrict__ aSsd, float* __restrict__ aDsd,
    u16* __restrict__ hd, float* __restrict__ aSds, float* __restrict__ aDds, int M)
{
  __shared__ __align__(16) float ldsf[4][16][148];
  const int t = threadIdx.x;

  if (blockIdx.x < NBLK) {
    // ---------------- bin path ----------------
    int* cur = (int*)&ldsf[0][0][0];        // 2346 ints
    int* s_bpre = cur + 3 * NBK;            // 256 ints
    compute_bpre(bsum, s_bpre);
    const int b = blockIdx.x;
    for (int i = t; i < 3 * NBK; i += 256) {
      const int idx = i * NBLK + b;
      cur[i] = scanned[idx] + s_bpre[idx >> 12];
    }
    __syncthreads();
    const int lo = b * CHT, hi = min(lo + CHT, ETT);
    for (int i = lo + t; i < hi; i += 256) {
      const int s = tt_src[i], d = tt_dst[i];
      int p = atomicAdd(&cur[d >> 7], 1);
      bin[p] = ((u32)(d & 127) << 17) | (u32)s;
      p = atomicAdd(&cur[NBK + (s >> 7)], 1);
      bin[p] = ((u32)(s & 127) << 17) | (u32)d;
    }
    const int lo2 = b * CHC, hi2 = min(lo2 + CHC, ECT);
    for (int i = lo2 + t; i < hi2; i += 256) {
      const int s = ect_s[i], d = ect_d[i];
      const int p = atomicAdd(&cur[2 * NBK + (d >> 7)], 1);
      bin[p] = ((u32)(d & 127) << 17) | (u32)s;
    }
    return;
  }
  logits2_body(ldsf, blockIdx.x - NBLK, A, Bsd, Bds,
               hs, aSsd, aDsd, hd, aSds, aDds, M);
}

// ---------- bucket_fill: standalone, small LDS ----------
__global__ __launch_bounds__(256) void bucket_fill_kernel(const int* __restrict__ scanned,
    const int* __restrict__ bsum, const u32* __restrict__ bin,
    int* __restrict__ offs, int* __restrict__ big_el)
{
  __shared__ int s_cnt[128], s_exc[128], s_cur[128], s_bpre[256];
  __shared__ int s_el[FILL_CAP];
  const int t = threadIdx.x;
  compute_bpre(bsum, s_bpre);
  const int rel = blockIdx.x / NBK;
  const int bucket = blockIdx.x - rel * NBK;
  if (t < 128) s_cnt[t] = 0;
  const int bi = blockIdx.x * NBLK;
  const int base = scanned[bi] + s_bpre[bi >> 12];
  const int nxt = (blockIdx.x == 3 * NBK - 1)
                      ? (2 * ETT + ECT)
                      : scanned[bi + NBLK] + s_bpre[(bi + NBLK) >> 12];
  __syncthreads();
  const int size = nxt - base;
  for (int i = t; i < size; i += 256)
    atomicAdd(&s_cnt[bin[base + i] >> 17], 1);
  __syncthreads();
  if (t < 128) s_exc[t] = s_cnt[t];
  __syncthreads();
  for (int d = 1; d < 128; d <<= 1) {
    int v = 0;
    if (t < 128 && t >= d) v = s_exc[t - d];
    __syncthreads();
    if (t < 128) s_exc[t] += v;
    __syncthreads();
  }
  const int relbase = rel * ETT;
  const int obase = base - relbase;
  int* off_rel = offs + (size_t)rel * OFFS;
  const int node0 = bucket * 128;
  if (t < 128) {
    const int excl = s_exc[t] - s_cnt[t];
    s_cur[t] = excl;                    // bucket-LOCAL cursor
    if (node0 + t < NT) off_rel[node0 + t] = obase + excl;
  }
  if (t == 0 && bucket == NBK - 1) off_rel[NT] = obase + size;
  __syncthreads();
  int* el_rel = big_el + relbase;
  if (size <= FILL_CAP) {
    for (int i = t; i < size; i += 256) {
      const u32 e = bin[base + i];
      const int pos = atomicAdd(&s_cur[e >> 17], 1);
      s_el[pos] = (int)(e & 0x1FFFFu);
    }
    __syncthreads();
    for (int i = t; i < size; i += 256)
      el_rel[obase + i] = s_el[i];
  } else {
    for (int i = t; i < size; i += 256) {
      const u32 e = bin[base + i];
      const int pos = atomicAdd(&s_cur[e >> 17], 1);
      el_rel[obase + pos] = (int)(e & 0x1FFFFu);
    }
  }
}

// ---------- mfma_out, ZERO-LDS: direct fragment-layout stores (verified R10) ----------
__global__ __launch_bounds__(256) void mfma_out_kernel(
    const short* __restrict__ A, const short* __restrict__ B,
    const float* __restrict__ bias, float* __restrict__ out, int M)
{
  const int t = threadIdx.x;
  const int wv = t >> 6, lane = t & 63;
  const int quad = lane >> 4, l16 = lane & 15;
  const int r0 = blockIdx.x * 64 + wv * 16;
  const int arow = min(r0 + l16, M - 1);
  const short* ap = A + (size_t)arow * 128 + quad * 8;
  bf16x8 af[4];
  for (int ks = 0; ks < 4; ++ks) af[ks] = *(const bf16x8*)(ap + ks * 32);
  f32x4 acc[8];
  for (int ti = 0; ti < 8; ++ti) acc[ti] = (f32x4){0.f, 0.f, 0.f, 0.f};
  for (int ks = 0; ks < 4; ++ks)
    for (int ti = 0; ti < 8; ++ti) {
      const bf16x8 bf = *(const bf16x8*)(B + ((ti * 4 + ks) * 64 + lane) * 8);
      acc[ti] = __builtin_amdgcn_mfma_f32_16x16x32_bf16(af[ks], bf, acc[ti], 0, 0, 0);
    }
  float bcol[8];
#pragma unroll
  for (int ti = 0; ti < 8; ++ti) bcol[ti] = bias[ti * 16 + l16];
#pragma unroll
  for (int r = 0; r < 4; ++r) {
    const int row = r0 + quad * 4 + r;
    if (row < M) {
      float* orow = out + (size_t)row * 128 + l16;
#pragma unroll
      for (int ti = 0; ti < 8; ++ti)
        orow[ti * 16] = acc[ti][r] + bcol[ti];
    }
  }
}

// ---------- K5: fused 3-relation gather (monolithic -- R0/R6 proven config) ----------
__device__ __forceinline__ void gat_pipe16(const int* __restrict__ off,
    const int* __restrict__ el, const float* __restrict__ aS, const float* __restrict__ aD,
    const u16* __restrict__ hb, int d, int h, int cb, int self_loop, float w,
    float* __restrict__ acc)
{
  const float ad = aD[(size_t)d * 4 + h];
  const int beg = off[d];
  const int m = off[d + 1] - beg;     // real edges
  const int cnt = m + self_loop;
  if (cnt <= 0) return;
  float den = 0.f;
  float a0 = 0.f, a1 = 0.f, a2 = 0.f, a3 = 0.f, a4 = 0.f, a5 = 0.f, a6 = 0.f, a7 = 0.f;
  int sB = (1 < m) ? el[beg + 1] : d;
  {
    const int sA0 = (0 < m) ? el[beg] : d;
    float eA = aS[(size_t)sA0 * 4 + h];
    uint4 pA = *(const uint4*)(hb + (size_t)sA0 * 128 + cb);
    for (int k = 0; k < cnt; ++k) {
      const int sC = (k + 2 < m) ? el[beg + k + 2] : d;
      const float eB = aS[(size_t)sB * 4 + h];
      const uint4 pB = *(const uint4*)(hb + (size_t)sB * 128 + cb);
      float ea = eA + ad;
      ea = ea > 0.f ? ea : SLOPE * ea;
      const float ex = exp2f(ea);
      den += ex;
      a0 = fmaf(ex, lof(pA.x), a0); a1 = fmaf(ex, hif(pA.x), a1);
      a2 = fmaf(ex, lof(pA.y), a2); a3 = fmaf(ex, hif(pA.y), a3);
      a4 = fmaf(ex, lof(pA.z), a4); a5 = fmaf(ex, hif(pA.z), a5);
      a6 = fmaf(ex, lof(pA.w), a6); a7 = fmaf(ex, hif(pA.w), a7);
      eA = eB; pA = pB; sB = sC;
    }
  }
  const float s = w / den;
  acc[0] = fmaf(a0, s, acc[0]); acc[1] = fmaf(a1, s, acc[1]);
  acc[2] = fmaf(a2, s, acc[2]); acc[3] = fmaf(a3, s, acc[3]);
  acc[4] = fmaf(a4, s, acc[4]); acc[5] = fmaf(a5, s, acc[5]);
  acc[6] = fmaf(a6, s, acc[6]); acc[7] = fmaf(a7, s, acc[7]);
}

__global__ __launch_bounds__(256) void gather_all_kernel(
    const int* __restrict__ off_f, const int* __restrict__ el_f,
    const float* __restrict__ aS_sd, const float* __restrict__ aD_sd, const u16* __restrict__ hs,
    const int* __restrict__ off_r, const int* __restrict__ el_r,
    const float* __restrict__ aS_ds, const float* __restrict__ aD_ds, const u16* __restrict__ hd,
    const int* __restrict__ off_c, const int* __restrict__ el_c,
    const float* __restrict__ aS_ct, const float* __restrict__ aD_ct, const u16* __restrict__ hc,
    const u16* __restrict__ skip, const float* __restrict__ cbias, u16* __restrict__ x)
{
  const int d = blockIdx.x * 16 + (threadIdx.x >> 4);
  if (d >= NT) return;
  const int lg = threadIdx.x & 15;    // lane in group
  const int h = lg >> 2;              // head for this lane's channels
  const int cb = lg * 8;              // channel base (8 channels per lane)
  float acc[8];
  for (int i = 0; i < 8; ++i) acc[i] = 0.f;
  gat_pipe16(off_f, el_f, aS_sd, aD_sd, hs, d, h, cb, 1, 0.25f, acc);
  gat_pipe16(off_r, el_r, aS_ds, aD_ds, hd, d, h, cb, 1, 0.25f, acc);
  gat_pipe16(off_c, el_c, aS_ct, aD_ct, hc, d, h, cb, 0, 0.5f, acc);
  const uint4 sk = *(const uint4*)(skip + (size_t)d * 128 + cb);
  const float4 cb0 = *(const float4*)(cbias + cb);
  const float4 cb1 = *(const float4*)(cbias + cb + 4);
  const float o0 = fmaxf(acc[0] + cb0.x + lof(sk.x), 0.f);
  const float o1 = fmaxf(acc[1] + cb0.y + hif(sk.x), 0.f);
  const float o2 = fmaxf(acc[2] + cb0.z + lof(sk.y), 0.f);
  const float o3 = fmaxf(acc[3] + cb0.w + hif(sk.y), 0.f);
  const float o4 = fmaxf(acc[4] + cb1.x + lof(sk.z), 0.f);
  const float o5 = fmaxf(acc[5] + cb1.y + hif(sk.z), 0.f);
  const float o6 = fmaxf(acc[6] + cb1.z + lof(sk.w), 0.f);
  const float o7 = fmaxf(acc[7] + cb1.w + hif(sk.w), 0.f);
  uint4 r;
  r.x = (u32)f2bf(o0) | ((u32)f2bf(o1) << 16);
  r.y = (u32)f2bf(o2) | ((u32)f2bf(o3) << 16);
  r.z = (u32)f2bf(o4) | ((u32)f2bf(o5) << 16);
  r.w = (u32)f2bf(o6) | ((u32)f2bf(o7) << 16);
  *(uint4*)(x + (size_t)d * 128 + cb) = r;
}

extern "C" void kernel_launch(void* const* d_in, const int* in_sizes, int n_in,
                              void* d_out, int out_size, void* d_ws, size_t ws_size,
                              hipStream_t stream)
{
  const float* x_t   = (const float*)d_in[0];
  const float* x_c   = (const float*)d_in[1];
  const int*   e_tt  = (const int*)d_in[2];
  const int*   ect_s = (const int*)d_in[3];
  const int*   ect_d = (const int*)d_in[4];
  const float* Wpt = (const float*)d_in[5];   const float* bpt = (const float*)d_in[6];
  const float* Wpc = (const float*)d_in[7];   const float* bpc = (const float*)d_in[8];
  const float* Wsd = (const float*)d_in[9];   const float* As_sd = (const float*)d_in[10];
  const float* Ad_sd = (const float*)d_in[11]; const float* bsd = (const float*)d_in[12];
  const float* Wds = (const float*)d_in[13];  const float* As_ds = (const float*)d_in[14];
  const float* Ad_ds = (const float*)d_in[15]; const float* bds = (const float*)d_in[16];
  const float* Wcs = (const float*)d_in[17];  const float* Wcd = (const float*)d_in[18];
  const float* As_ct = (const float*)d_in[19]; const float* Ad_ct = (const float*)d_in[20];
  const float* bct = (const float*)d_in[21];
  const float* Wout = (const float*)d_in[22]; const float* bout = (const float*)d_in[23];

  // workspace
  char* p = (char*)d_ws;
  size_t off = 0;
  auto alloc = [&](size_t bytes) { char* r = p + off; off += (bytes + 255) & ~(size_t)255; return r; };
  u16* ht_bf   = (u16*)alloc((size_t)NT * 128 * 2);
  u16* hs_bf   = (u16*)alloc((size_t)NT * 128 * 2);
  u16* hd_bf   = (u16*)alloc((size_t)NT * 128 * 2);
  u16* hc_bf   = (u16*)alloc((size_t)NC * 128 * 2);
  u16* x_bf    = (u16*)alloc((size_t)NT * 128 * 2);
  float* aS_sd = (float*)alloc((size_t)NT * 4 * 4);
  float* aD_sd = (float*)alloc((size_t)NT * 4 * 4);
  float* aS_ds = (float*)alloc((size_t)NT * 4 * 4);
  float* aD_ds = (float*)alloc((size_t)NT * 4 * 4);
  float* aS_ct = (float*)alloc((size_t)NC * 4 * 4);
  float* aD_ct = (float*)alloc((size_t)NT * 4 * 4);
  int* cntblk  = (int*)alloc((size_t)TOTC * 4);
  int* scanned = (int*)alloc((size_t)TOTC * 4);
  u32* bin     = (u32*)alloc((size_t)(2 * ETT + ECT) * 4);
  int* big_el  = (int*)alloc((size_t)(2 * ETT + ECT) * 4);
  int* offs    = (int*)alloc((size_t)3 * OFFS * 4);
  int* bsum    = (int*)alloc((size_t)NSB * 4);
  float* cbias   = (float*)alloc(128 * 4);
  u16* bfrag_sd  = (u16*)alloc((size_t)9 * 4 * 64 * 8 * 2);
  u16* bfrag_ds  = (u16*)alloc((size_t)9 * 4 * 64 * 8 * 2);
  u16* bfrag_out = (u16*)alloc((size_t)8 * 4 * 64 * 8 * 2);

  int* off_f = offs;
  int* off_r = offs + OFFS;
  int* off_c = offs + 2 * OFFS;
  int* el_f = big_el;
  int* el_r = big_el + ETT;
  int* el_c = big_el + 2 * ETT;

  const int* tt_src = e_tt;
  const int* tt_dst = e_tt + ETT;

  // K_A: hist ∪ prep ∪ pre_t ∪ ctx (all paths <=27648B LDS -> 5 blocks/CU)
  transform_hist_kernel<<<NBLK + 4 + PT_BLK + CT_BLK, 256, 0, stream>>>(
      tt_src, tt_dst, ect_d, cntblk,
      Wsd, As_sd, Ad_sd, Wds, As_ds, Ad_ds, Wout,
      bfrag_sd, bfrag_ds, bfrag_out,
      Wcd, Ad_ct, bsd, bds, bct, cbias,
      x_t, Wpt, bpt, ht_bf, aD_ct,
      x_c, Wpc, bpc, Wcs, As_ct, hc_bf, aS_ct);

  // scan
  scan2_blk_kernel<<<NSB, 256, 0, stream>>>(cntblk, scanned, bsum);

  // K_C: bin ∪ logits2
  bin_logits2_kernel<<<NBLK + GM_BLK, 256, 0, stream>>>(
      tt_src, tt_dst, ect_s, ect_d, scanned, bsum, bin,
      (const short*)ht_bf, (const short*)bfrag_sd, (const short*)bfrag_ds,
      hs_bf, aS_sd, aD_sd, hd_bf, aS_ds, aD_ds, NT);

  // bucket_fill
  bucket_fill_kernel<<<3 * NBK, 256, 0, stream>>>(scanned, bsum, bin, offs, big_el);

  // fused gather (monolithic -- proven fastest config)
  gather_all_kernel<<<(NT + 15) / 16, 256, 0, stream>>>(
      off_f, el_f, aS_sd, aD_sd, hs_bf,
      off_r, el_r, aS_ds, aD_ds, hd_bf,
      off_c, el_c, aS_ct, aD_ct, hc_bf,
      ht_bf, cbias, x_bf);

  // final MFMA GEMM -> d_out (zero-LDS direct stores)
  mfma_out_kernel<<<GM_BLK, 256, 0, stream>>>((const short*)x_bf, (const short*)bfrag_out,
                                              bout, (float*)d_out, NT);
}